// Round 9
// baseline (6505.379 us; speedup 1.0000x reference)
//
#include <hip/hip_runtime.h>
#include <hip/hip_bf16.h>
#include <math.h>

#define N_Q 2048
#define K_E 32
#define D_F 128
#define H_N 8
#define DH_N 16
#define EPS_F 1e-5f
#define NEGMAX -3.4028235e38f
#define EPB 8      // edges per E1 block
#define ECON 4     // edges processed concurrently

// dtypes (established): fp32 inputs, int32 mask/knn, FP32 output.

// ---------------------------------------------------------------------------
// Kernel A+B merged: query LN+Wq (blocks [0,N)) and key Wk (blocks [N,2N))
// ---------------------------------------------------------------------------
__global__ __launch_bounds__(128) void k_qk(
    const float* __restrict__ qs_in, const float* __restrict__ qv_in,
    const float* __restrict__ ks_in, const float* __restrict__ kv_in,
    const float* __restrict__ Wq_s, const float* __restrict__ Wq_v, const float* __restrict__ bq,
    const float* __restrict__ Wk_s, const float* __restrict__ Wk_v, const float* __restrict__ bk,
    const float* __restrict__ ln_gs, const float* __restrict__ ln_bs, const float* __restrict__ ln_gv,
    float* __restrict__ qs2, float* __restrict__ qv2,
    float* __restrict__ skip_s, float* __restrict__ skip_v,
    float* __restrict__ ksc, float* __restrict__ kvc)
{
    const int t = threadIdx.x;
    __shared__ float s[D_F], v[D_F*3], sl[D_F], vl[D_F*3];
    if (blockIdx.x < N_Q) {
        const int n = blockIdx.x;
        s[t] = qs_in[n*D_F + t];
        #pragma unroll
        for (int x = 0; x < 3; ++x) v[t*3+x] = qv_in[(n*D_F + t)*3 + x];
        __syncthreads();
        float mu = 0.f;
        for (int i = 0; i < D_F; ++i) mu += s[i];
        mu *= (1.f/D_F);
        float var = 0.f;
        for (int i = 0; i < D_F; ++i) { float d = s[i]-mu; var += d*d; }
        var *= (1.f/D_F);
        float rstd = rsqrtf(var + EPS_F);
        float ssq = 0.f;
        for (int i = 0; i < D_F*3; ++i) ssq += v[i]*v[i];
        float rrms = rsqrtf(ssq*(1.f/D_F) + EPS_F);
        float a = (s[t]-mu)*rstd*ln_gs[t] + ln_bs[t];
        sl[t] = a; skip_s[n*D_F + t] = a;
        float gv = ln_gv[t];
        #pragma unroll
        for (int x = 0; x < 3; ++x) {
            float b = v[t*3+x]*rrms*gv;
            vl[t*3+x] = b; skip_v[(n*D_F + t)*3 + x] = b;
        }
        __syncthreads();
        float acc = bq[t], a0 = 0.f, a1 = 0.f, a2 = 0.f;
        for (int i = 0; i < D_F; ++i) {
            float ws = Wq_s[i*D_F + t]; acc += sl[i]*ws;
            float wv = Wq_v[i*D_F + t];
            a0 += vl[i*3+0]*wv; a1 += vl[i*3+1]*wv; a2 += vl[i*3+2]*wv;
        }
        qs2[n*D_F + t] = acc;
        qv2[(n*D_F + t)*3 + 0] = a0;
        qv2[(n*D_F + t)*3 + 1] = a1;
        qv2[(n*D_F + t)*3 + 2] = a2;
    } else {
        const int n = blockIdx.x - N_Q;
        s[t] = ks_in[n*D_F + t];
        #pragma unroll
        for (int x = 0; x < 3; ++x) v[t*3+x] = kv_in[(n*D_F + t)*3 + x];
        __syncthreads();
        float acc = bk[t], a0 = 0.f, a1 = 0.f, a2 = 0.f;
        for (int i = 0; i < D_F; ++i) {
            float ws = Wk_s[i*D_F + t]; acc += s[i]*ws;
            float wv = Wk_v[i*D_F + t];
            a0 += v[i*3+0]*wv; a1 += v[i*3+1]*wv; a2 += v[i*3+2]*wv;
        }
        ksc[n*D_F + t] = acc;
        kvc[(n*D_F + t)*3 + 0] = a0;
        kvc[(n*D_F + t)*3 + 1] = a1;
        kvc[(n*D_F + t)*3 + 2] = a2;
    }
}

// ---------------------------------------------------------------------------
// E1: bulk edge pipeline. Block = 8 edges (one n), 512 threads, 4 edges
// concurrent. Computes w inline, writes per-edge values to ebuf and raw
// logits to attn_out. No softmax here (edges fully parallel).
// ---------------------------------------------------------------------------
__global__ __launch_bounds__(512, 4) void k_edge_bulk(
    const float* __restrict__ qs2, const float* __restrict__ qv2,
    const float* __restrict__ ksc, const float* __restrict__ kvc,
    const float* __restrict__ eis, const float* __restrict__ eiv,
    const float* __restrict__ eemb,
    const int* __restrict__ mask, const int* __restrict__ knn,
    const float* __restrict__ Wqk_s, const float* __restrict__ Wqk_v, const float* __restrict__ bqk,
    const float* __restrict__ Wdtp, const float* __restrict__ bdtp,
    const float* __restrict__ Wagv_s, const float* __restrict__ bagv, const float* __restrict__ Wagv_v,
    const float* __restrict__ Wattn, const float* __restrict__ lna_g, const float* __restrict__ lna_b,
    const float* __restrict__ Wval_s, const float* __restrict__ Wval_v, const float* __restrict__ bval,
    float* __restrict__ ebuf, float* __restrict__ attn_raw)
{
    const int t = threadIdx.x;
    const int e0 = blockIdx.x * EPB;
    const int n  = e0 >> 5;
    const int k0 = e0 & 31;
    const int s = t >> 7, c = t & 127, h = (t >> 4) & 7, o = t & 15;

    __shared__ float w_lds[EPB*512];      // 16 KB
    __shared__ float arena[11264];        // 44 KB (ee aliased in stage A)
    __shared__ float sh_qs[D_F], sh_qv[D_F*3];
    __shared__ float sh_es[ECON], sh_ev[ECON*3];

    float* ks_b  = arena;                 // [4][128]
    float* kv_b  = arena + 512;           // [4][384]
    float* cs_b  = arena + 2048;          // [4][256]
    float* cv_b  = arena + 3072;          // [4][768]
    float* ps_b  = arena + 6144;          // [4][128]
    float* pv_b  = arena + 6656;          // [4][384]
    float* agv_b = arena + 8192;          // [4][384]
    float* vv_b  = arena + 9728;          // [4][384]
    float* ee    = arena;                 // [128][8], stage A only

    if (t < D_F) sh_qs[t] = qs2[n*D_F + t];
    if (t < D_F*3 && t >= D_F) sh_qv[t-D_F] = qv2[n*D_F*3 + (t-D_F)];
    // remaining 2/3 of qv:
    { int idx = t + 384; if (idx >= D_F && idx < D_F + D_F*3) sh_qv[idx-D_F] = qv2[n*D_F*3 + (idx-D_F)]; }

    // stage A: ee load (transposed) + w GEMM into LDS
    { int idx = t;       int m = idx & 7, i = idx >> 3; ee[i*EPB+m] = eemb[(size_t)(e0+m)*D_F + i]; }
    { int idx = t + 512; int m = idx & 7, i = idx >> 3; ee[i*EPB+m] = eemb[(size_t)(e0+m)*D_F + i]; }
    __syncthreads();
    {
        float acc[EPB];
        float b = bdtp[t];
        #pragma unroll
        for (int m = 0; m < EPB; ++m) acc[m] = b;
        for (int i = 0; i < D_F; ++i) {
            float wv = Wdtp[i*512 + t];
            #pragma unroll
            for (int m = 0; m < EPB; ++m) acc[m] += ee[i*EPB+m]*wv;
        }
        __syncthreads();              // ee dead -> arena reusable
        #pragma unroll
        for (int m = 0; m < EPB; ++m) w_lds[m*512 + t] = acc[m];
    }

    const float bqk_r  = bqk[o];
    const float bval_r = bval[o];
    const float bag0 = bagv[h*48 + o];
    const float bag1 = bagv[h*48 + 16 + o];
    const float bag2 = bagv[h*48 + 32 + o];
    const int tA = h*32 + o, tB = h*32 + 16 + o;

    for (int p = 0; p < EPB/ECON; ++p) {
        const int m = p*ECON + s;
        const int e = e0 + m;
        // B0: stage k row + edge irreps
        {
            const int j = knn[e];
            ks_b[s*128 + c] = ksc[j*D_F + c];
            #pragma unroll
            for (int r = 0; r < 3; ++r)
                kv_b[s*384 + c + r*128] = kvc[(size_t)j*D_F*3 + c + r*128];
            if (c == 0) {
                sh_es[s] = eis[e];
                sh_ev[s*3+0] = eiv[e*3+0]; sh_ev[s*3+1] = eiv[e*3+1]; sh_ev[s*3+2] = eiv[e*3+2];
            }
        }
        __syncthreads();
        // B1: dtp1
        {
            float s1 = sh_qs[c], kd = ks_b[s*128+c];
            float q0 = sh_qv[c*3+0], q1 = sh_qv[c*3+1], q2 = sh_qv[c*3+2];
            float k0v = kv_b[s*384 + c*3+0], k1v = kv_b[s*384 + c*3+1], k2v = kv_b[s*384 + c*3+2];
            cs_b[s*256 + c]       = s1*kd;
            cs_b[s*256 + 128 + c] = q0*k0v + q1*k1v + q2*k2v;
            cv_b[s*768 + c*3+0] = s1*k0v; cv_b[s*768 + c*3+1] = s1*k1v; cv_b[s*768 + c*3+2] = s1*k2v;
            cv_b[s*768 + (128+c)*3+0] = kd*q0; cv_b[s*768 + (128+c)*3+1] = kd*q1; cv_b[s*768 + (128+c)*3+2] = kd*q2;
        }
        __syncthreads();
        // B2: Wqk
        {
            float as = bqk_r, av0=0.f, av1=0.f, av2=0.f;
            for (int ii = 0; ii < 32; ++ii) {
                int i = (ii + h*8) & 31;
                int cb = h*32 + i;
                float ws = Wqk_s[i*16 + o];
                as += cs_b[s*256 + cb]*ws;
                float wv = Wqk_v[i*16 + o];
                av0 += cv_b[s*768 + cb*3+0]*wv;
                av1 += cv_b[s*768 + cb*3+1]*wv;
                av2 += cv_b[s*768 + cb*3+2]*wv;
            }
            ps_b[s*128 + c] = as;
            pv_b[s*384 + c*3+0] = av0; pv_b[s*384 + c*3+1] = av1; pv_b[s*384 + c*3+2] = av2;
        }
        __syncthreads();
        // B3: dtp2 (weighted)
        {
            const float* wm = &w_lds[m*512];
            float es = sh_es[s];
            float evx = sh_ev[s*3+0], evy = sh_ev[s*3+1], evz = sh_ev[s*3+2];
            float s1 = ps_b[s*128 + c];
            float w0 = wm[c], w1 = wm[128+c], w2 = wm[256+c], w3 = wm[384+c];
            cs_b[s*256 + tA] = s1*es*w0;
            cv_b[s*768 + tA*3+0] = s1*evx*w2; cv_b[s*768 + tA*3+1] = s1*evy*w2; cv_b[s*768 + tA*3+2] = s1*evz*w2;
            float p0 = pv_b[s*384 + c*3+0], p1 = pv_b[s*384 + c*3+1], p2 = pv_b[s*384 + c*3+2];
            cs_b[s*256 + tB] = (p0*evx + p1*evy + p2*evz)*w1;
            cv_b[s*768 + tB*3+0] = es*p0*w3; cv_b[s*768 + tB*3+1] = es*p1*w3; cv_b[s*768 + tB*3+2] = es*p2*w3;
        }
        __syncthreads();
        // B4: Wagv
        {
            float aatt = bag0, agate = bag1, avals = bag2;
            float v0=0.f, v1=0.f, v2=0.f;
            for (int ii = 0; ii < 32; ++ii) {
                int i = (ii + h*8) & 31;
                int cb = h*32 + i;
                float a_s = cs_b[s*256 + cb];
                const float* wrow = &Wagv_s[(h*32+i)*48];
                aatt  += a_s*wrow[o];
                agate += a_s*wrow[16+o];
                avals += a_s*wrow[32+o];
                float wv = Wagv_v[(h*32+i)*16 + o];
                v0 += cv_b[s*768 + cb*3+0]*wv;
                v1 += cv_b[s*768 + cb*3+1]*wv;
                v2 += cv_b[s*768 + cb*3+2]*wv;
            }
            agv_b[s*384 + h*48 + o]      = aatt;
            agv_b[s*384 + h*48 + 16 + o] = agate;
            agv_b[s*384 + h*48 + 32 + o] = avals;
            vv_b[s*384 + c*3+0] = v0; vv_b[s*384 + c*3+1] = v1; vv_b[s*384 + c*3+2] = v2;
        }
        __syncthreads();
        // B5: logit (t<32 -> 4 edges x 8 heads) + gating (all threads)
        if (t < ECON*H_N) {
            int s2 = t >> 3, h2 = t & 7;
            const float* af = &agv_b[s2*384 + h2*48];
            float mu = 0.f;
            for (int d2 = 0; d2 < DH_N; ++d2) mu += af[d2];
            mu *= (1.f/DH_N);
            float var = 0.f;
            for (int d2 = 0; d2 < DH_N; ++d2) { float dd = af[d2]-mu; var += dd*dd; }
            var *= (1.f/DH_N);
            float rstd = rsqrtf(var + EPS_F);
            float logit = 0.f;
            for (int d2 = 0; d2 < DH_N; ++d2) {
                float xn = (af[d2]-mu)*rstd*lna_g[d2] + lna_b[d2];
                logit += xn*Wattn[d2];
            }
            int e2 = e0 + p*ECON + s2;
            if (mask[e2] == 0) logit = NEGMAX;
            attn_raw[h2*(N_Q*K_E) + n*K_E + (k0 + p*ECON + s2)] = logit;
        }
        {
            float vraw = agv_b[s*384 + h*48 + 32 + o];
            float sact = vraw / (1.f + expf(-vraw));
            float g = 1.f / (1.f + expf(-agv_b[s*384 + h*48 + 16 + o]));
            ps_b[s*128 + c] = sact;
            pv_b[s*384 + c*3+0] = vv_b[s*384 + c*3+0]*g;
            pv_b[s*384 + c*3+1] = vv_b[s*384 + c*3+1]*g;
            pv_b[s*384 + c*3+2] = vv_b[s*384 + c*3+2]*g;
        }
        __syncthreads();
        // B6: dtp3
        {
            float es = sh_es[s];
            float evx = sh_ev[s*3+0], evy = sh_ev[s*3+1], evz = sh_ev[s*3+2];
            float s1 = ps_b[s*128 + c];
            cs_b[s*256 + tA] = s1*es;
            cv_b[s*768 + tA*3+0] = s1*evx; cv_b[s*768 + tA*3+1] = s1*evy; cv_b[s*768 + tA*3+2] = s1*evz;
            float p0 = pv_b[s*384 + c*3+0], p1 = pv_b[s*384 + c*3+1], p2 = pv_b[s*384 + c*3+2];
            cs_b[s*256 + tB] = p0*evx + p1*evy + p2*evz;
            cv_b[s*768 + tB*3+0] = es*p0; cv_b[s*768 + tB*3+1] = es*p1; cv_b[s*768 + tB*3+2] = es*p2;
        }
        __syncthreads();
        // B7: Wval -> ebuf
        {
            float vs = bval_r, v0=0.f, v1=0.f, v2=0.f;
            for (int ii = 0; ii < 32; ++ii) {
                int i = (ii + h*8) & 31;
                int cb = h*32 + i;
                float ws = Wval_s[i*16 + o];
                vs += cs_b[s*256 + cb]*ws;
                float wv = Wval_v[i*16 + o];
                v0 += cv_b[s*768 + cb*3+0]*wv;
                v1 += cv_b[s*768 + cb*3+1]*wv;
                v2 += cv_b[s*768 + cb*3+2]*wv;
            }
            float* eb = &ebuf[(size_t)e*512];
            eb[c] = vs;
            eb[128 + c*3+0] = v0; eb[128 + c*3+1] = v1; eb[128 + c*3+2] = v2;
        }
        __syncthreads();
    }
}

// ---------------------------------------------------------------------------
// E2: per-n softmax (raw logits in attn buffer) + attention-weighted sum
// ---------------------------------------------------------------------------
__global__ __launch_bounds__(128) void k_reduce(
    const float* __restrict__ ebuf,
    float* __restrict__ attn_out,     // in: raw logits, out: probabilities
    float* __restrict__ outs_pre, float* __restrict__ outv_pre)
{
    const int n = blockIdx.x, t = threadIdx.x;
    __shared__ float sh_attn[H_N*K_E];
    if (t < H_N) {
        float lg[K_E];
        float mx = NEGMAX;
        for (int k = 0; k < K_E; ++k) {
            lg[k] = attn_out[t*(N_Q*K_E) + n*K_E + k];
            mx = fmaxf(mx, lg[k]);
        }
        float sum = 0.f;
        for (int k = 0; k < K_E; ++k) { float p = expf(lg[k]-mx); lg[k] = p; sum += p; }
        float rinv = 1.f/sum;
        for (int k = 0; k < K_E; ++k) {
            float a = lg[k]*rinv;
            sh_attn[t*K_E + k] = a;
            attn_out[t*(N_Q*K_E) + n*K_E + k] = a;
        }
    }
    __syncthreads();
    const int h = t >> 4;
    float accs = 0.f, a0 = 0.f, a1 = 0.f, a2 = 0.f;
    for (int k = 0; k < K_E; ++k) {
        float a = sh_attn[h*K_E + k];
        const float* eb = &ebuf[(size_t)(n*K_E + k)*512];
        accs += a*eb[t];
        a0 += a*eb[128 + t*3+0];
        a1 += a*eb[128 + t*3+1];
        a2 += a*eb[128 + t*3+2];
    }
    outs_pre[n*D_F + t] = accs;
    outv_pre[(n*D_F+t)*3+0] = a0;
    outv_pre[(n*D_F+t)*3+1] = a1;
    outv_pre[(n*D_F+t)*3+2] = a2;
}

// ---------------------------------------------------------------------------
// Fallback (round-7 monolithic, needs only 16*N*D scratch)
// ---------------------------------------------------------------------------
__global__ __launch_bounds__(256) void k_edge(
    const float* __restrict__ qs2, const float* __restrict__ qv2,
    const float* __restrict__ ksc, const float* __restrict__ kvc,
    const float* __restrict__ eis, const float* __restrict__ eiv,
    const float* __restrict__ eemb,
    const int* __restrict__ mask, const int* __restrict__ knn,
    const float* __restrict__ Wqk_s, const float* __restrict__ Wqk_v, const float* __restrict__ bqk,
    const float* __restrict__ Wdtp, const float* __restrict__ bdtp,
    const float* __restrict__ Wagv_s, const float* __restrict__ bagv, const float* __restrict__ Wagv_v,
    const float* __restrict__ Wattn, const float* __restrict__ lna_g, const float* __restrict__ lna_b,
    const float* __restrict__ Wval_s, const float* __restrict__ Wval_v, const float* __restrict__ bval,
    float* __restrict__ outs_pre, float* __restrict__ outv_pre,
    float* __restrict__ attn_out)
{
    const int n = blockIdx.x, t = threadIdx.x;
    __shared__ float sh_qs[D_F], sh_qv[D_F*3];
    __shared__ float sh_ks[D_F], sh_kv[D_F*3], sh_ee[D_F];
    __shared__ float sh_cs[2*D_F], sh_cv[2*D_F*3];
    __shared__ float sh_ps[D_F], sh_pv[D_F*3];
    __shared__ float sh_w[4*D_F];
    __shared__ float sh_agv[H_N*48], sh_valv[H_N*DH_N*3];
    __shared__ float sh_logit[H_N*K_E], sh_red[H_N*2];
    __shared__ float sh_es, sh_ev[3];
    float m_run = NEGMAX, l_run = 0.f;
    float accs = 0.f, acc0 = 0.f, acc1 = 0.f, acc2 = 0.f;
    if (t < D_F) sh_qs[t] = qs2[n*D_F + t];
    for (int idx = t; idx < D_F*3; idx += 256) sh_qv[idx] = qv2[n*D_F*3 + idx];
    for (int k = 0; k < K_E; ++k) {
        const int e = n*K_E + k;
        const int j = knn[e];
        if (t < D_F) { sh_ks[t] = ksc[j*D_F + t]; sh_ee[t] = eemb[e*D_F + t]; }
        for (int idx = t; idx < D_F*3; idx += 256) sh_kv[idx] = kvc[j*D_F*3 + idx];
        if (t == 0) {
            sh_es = eis[e];
            sh_ev[0] = eiv[e*3+0]; sh_ev[1] = eiv[e*3+1]; sh_ev[2] = eiv[e*3+2];
        }
        __syncthreads();
        {
            const int c = t;
            if (c < D_F) {
                float s1 = sh_qs[c];
                sh_cs[c] = s1 * sh_ks[c];
                #pragma unroll
                for (int x = 0; x < 3; ++x) sh_cv[c*3+x] = s1 * sh_kv[c*3+x];
            } else {
                int d = c - D_F;
                float dot = 0.f;
                #pragma unroll
                for (int x = 0; x < 3; ++x) dot += sh_qv[d*3+x]*sh_kv[d*3+x];
                sh_cs[c] = dot;
                #pragma unroll
                for (int x = 0; x < 3; ++x) sh_cv[c*3+x] = sh_ks[d]*sh_qv[d*3+x];
            }
        }
        __syncthreads();
        #pragma unroll
        for (int r = 0; r < 2; ++r) {
            int oo = t + r*256;
            float acc = bdtp[oo];
            for (int i = 0; i < D_F; ++i) acc += sh_ee[i]*Wdtp[i*512 + oo];
            sh_w[oo] = acc;
        }
        if (t < D_F) {
            int h = t >> 4, o = t & 15;
            float as = bqk[o], av0 = 0.f, av1 = 0.f, av2 = 0.f;
            for (int i = 0; i < 32; ++i) {
                int cb = h*32 + i;
                float ws = Wqk_s[i*16 + o];
                as += sh_cs[cb]*ws;
                float wv = Wqk_v[i*16 + o];
                av0 += sh_cv[cb*3+0]*wv; av1 += sh_cv[cb*3+1]*wv; av2 += sh_cv[cb*3+2]*wv;
            }
            sh_ps[t] = as;
            sh_pv[t*3+0] = av0; sh_pv[t*3+1] = av1; sh_pv[t*3+2] = av2;
        }
        __syncthreads();
        {
            int h = t >> 5, i = t & 31;
            float es = sh_es;
            if (i < DH_N) {
                int cc = h*DH_N + i;
                float s1 = sh_ps[cc];
                sh_cs[t] = s1*es*sh_w[0*D_F + cc];
                float w2 = sh_w[2*D_F + cc];
                #pragma unroll
                for (int x = 0; x < 3; ++x) sh_cv[t*3+x] = s1*sh_ev[x]*w2;
            } else {
                int cc = h*DH_N + (i - DH_N);
                float dot = 0.f;
                #pragma unroll
                for (int x = 0; x < 3; ++x) dot += sh_pv[cc*3+x]*sh_ev[x];
                sh_cs[t] = dot*sh_w[1*D_F + cc];
                float w3 = sh_w[3*D_F + cc];
                #pragma unroll
                for (int x = 0; x < 3; ++x) sh_cv[t*3+x] = es*sh_pv[cc*3+x]*w3;
            }
        }
        __syncthreads();
        for (int idx = t; idx < H_N*48; idx += 256) {
            int h = idx / 48, oo = idx % 48;
            float acc = bagv[h*48 + oo];
            for (int i = 0; i < 32; ++i)
                acc += sh_cs[h*32 + i]*Wagv_s[(h*32 + i)*48 + oo];
            sh_agv[idx] = acc;
        }
        if (t < D_F) {
            int h = t >> 4, o = t & 15;
            float a0 = 0.f, a1 = 0.f, a2 = 0.f;
            for (int i = 0; i < 32; ++i) {
                float wv = Wagv_v[(h*32 + i)*16 + o];
                a0 += sh_cv[(h*32+i)*3+0]*wv;
                a1 += sh_cv[(h*32+i)*3+1]*wv;
                a2 += sh_cv[(h*32+i)*3+2]*wv;
            }
            sh_valv[t*3+0] = a0; sh_valv[t*3+1] = a1; sh_valv[t*3+2] = a2;
        }
        __syncthreads();
        if (t < H_N) {
            const float* af = &sh_agv[t*48];
            float mu = 0.f;
            for (int d2 = 0; d2 < DH_N; ++d2) mu += af[d2];
            mu *= (1.f/DH_N);
            float var = 0.f;
            for (int d2 = 0; d2 < DH_N; ++d2) { float dd = af[d2]-mu; var += dd*dd; }
            var *= (1.f/DH_N);
            float rstd = rsqrtf(var + EPS_F);
            float logit = 0.f;
            for (int d2 = 0; d2 < DH_N; ++d2) {
                float xn = (af[d2]-mu)*rstd*lna_g[d2] + lna_b[d2];
                logit += xn*Wattn[d2];
            }
            if (mask[e] == 0) logit = NEGMAX;
            sh_logit[t*K_E + k] = logit;
            float m_new = fmaxf(m_run, logit);
            float alpha = expf(m_run - m_new);
            float p     = expf(logit - m_new);
            l_run = l_run*alpha + p;
            m_run = m_new;
            sh_red[t*2]   = alpha;
            sh_red[t*2+1] = p;
        }
        if (t < D_F) {
            int h = t >> 4, o = t & 15;
            float vraw = sh_agv[h*48 + 32 + o];
            float sact = vraw / (1.f + expf(-vraw));
            float g = 1.f / (1.f + expf(-sh_agv[h*48 + 16 + o]));
            sh_ps[t] = sact;
            #pragma unroll
            for (int x = 0; x < 3; ++x) sh_pv[t*3+x] = sh_valv[t*3+x]*g;
        }
        __syncthreads();
        {
            int h = t >> 5, i = t & 31;
            if (i < DH_N) {
                int cc = h*DH_N + i;
                float s1 = sh_ps[cc];
                sh_cs[t] = s1*sh_es;
                #pragma unroll
                for (int x = 0; x < 3; ++x) sh_cv[t*3+x] = s1*sh_ev[x];
            } else {
                int cc = h*DH_N + (i - DH_N);
                float dot = 0.f;
                #pragma unroll
                for (int x = 0; x < 3; ++x) dot += sh_pv[cc*3+x]*sh_ev[x];
                sh_cs[t] = dot;
                #pragma unroll
                for (int x = 0; x < 3; ++x) sh_cv[t*3+x] = sh_es*sh_pv[cc*3+x];
            }
        }
        __syncthreads();
        if (t < D_F) {
            int h = t >> 4, o = t & 15;
            float vs = bval[o], v0 = 0.f, v1 = 0.f, v2 = 0.f;
            for (int i = 0; i < 32; ++i) {
                int cb = h*32 + i;
                float ws = Wval_s[i*16 + o];
                vs += sh_cs[cb]*ws;
                float wv = Wval_v[i*16 + o];
                v0 += sh_cv[cb*3+0]*wv; v1 += sh_cv[cb*3+1]*wv; v2 += sh_cv[cb*3+2]*wv;
            }
            float alpha = sh_red[h*2], p = sh_red[h*2+1];
            accs = accs*alpha + p*vs;
            acc0 = acc0*alpha + p*v0;
            acc1 = acc1*alpha + p*v1;
            acc2 = acc2*alpha + p*v2;
        }
        __syncthreads();
    }
    if (t < H_N) {
        sh_red[t*2]   = m_run;
        sh_red[t*2+1] = 1.f / l_run;
    }
    __syncthreads();
    {
        int h = t >> 5, k = t & 31;
        float a = expf(sh_logit[t] - sh_red[h*2]) * sh_red[h*2+1];
        attn_out[h*(N_Q*K_E) + n*K_E + k] = a;
    }
    if (t < D_F) {
        int h = t >> 4;
        float rinv = sh_red[h*2+1];
        outs_pre[n*D_F + t]     = accs*rinv;
        outv_pre[(n*D_F+t)*3+0] = acc0*rinv;
        outv_pre[(n*D_F+t)*3+1] = acc1*rinv;
        outv_pre[(n*D_F+t)*3+2] = acc2*rinv;
    }
}

// ---------------------------------------------------------------------------
// Kernel D: output eq_linear(Wo) + skip add
// ---------------------------------------------------------------------------
__global__ __launch_bounds__(128) void k_out(
    const float* __restrict__ outs_pre, const float* __restrict__ outv_pre,
    const float* __restrict__ skip_s, const float* __restrict__ skip_v,
    const float* __restrict__ Wo_s, const float* __restrict__ Wo_v, const float* __restrict__ bo,
    float* __restrict__ out0, float* __restrict__ out1)
{
    const int n = blockIdx.x, t = threadIdx.x;
    __shared__ float ps[D_F], pv[D_F*3];
    ps[t] = outs_pre[n*D_F + t];
    #pragma unroll
    for (int x = 0; x < 3; ++x) pv[t*3+x] = outv_pre[(n*D_F + t)*3 + x];
    __syncthreads();
    float acc = bo[t], a0 = 0.f, a1 = 0.f, a2 = 0.f;
    for (int i = 0; i < D_F; ++i) {
        float ws = Wo_s[i*D_F + t]; acc += ps[i]*ws;
        float wv = Wo_v[i*D_F + t];
        a0 += pv[i*3+0]*wv; a1 += pv[i*3+1]*wv; a2 += pv[i*3+2]*wv;
    }
    out0[n*D_F + t] = acc + skip_s[n*D_F + t];
    out1[(n*D_F + t)*3 + 0] = a0 + skip_v[(n*D_F + t)*3 + 0];
    out1[(n*D_F + t)*3 + 1] = a1 + skip_v[(n*D_F + t)*3 + 1];
    out1[(n*D_F + t)*3 + 2] = a2 + skip_v[(n*D_F + t)*3 + 2];
}

// ---------------------------------------------------------------------------
extern "C" void kernel_launch(void* const* d_in, const int* in_sizes, int n_in,
                              void* d_out, int out_size, void* d_ws, size_t ws_size,
                              hipStream_t stream)
{
    (void)in_sizes; (void)n_in; (void)out_size;

    const float* query_s = (const float*)d_in[0];
    const float* query_v = (const float*)d_in[1];
    const float* key_s   = (const float*)d_in[2];
    const float* key_v   = (const float*)d_in[3];
    const float* eis     = (const float*)d_in[4];
    const float* eiv     = (const float*)d_in[5];
    const float* eemb    = (const float*)d_in[6];
    const int*   mask    = (const int*)d_in[7];
    const int*   knn     = (const int*)d_in[8];
    const float* Wq_s    = (const float*)d_in[9];
    const float* Wq_v    = (const float*)d_in[10];
    const float* bq      = (const float*)d_in[11];
    const float* Wk_s    = (const float*)d_in[12];
    const float* Wk_v    = (const float*)d_in[13];
    const float* bk      = (const float*)d_in[14];
    const float* Wqk_s   = (const float*)d_in[15];
    const float* Wqk_v   = (const float*)d_in[16];
    const float* bqk     = (const float*)d_in[17];
    const float* Wdtp    = (const float*)d_in[18];
    const float* bdtp    = (const float*)d_in[19];
    const float* Wagv_s  = (const float*)d_in[20];
    const float* bagv    = (const float*)d_in[21];
    const float* Wagv_v  = (const float*)d_in[22];
    const float* Wattn   = (const float*)d_in[23];
    const float* Wval_s  = (const float*)d_in[24];
    const float* Wval_v  = (const float*)d_in[25];
    const float* bval    = (const float*)d_in[26];
    const float* Wo_s    = (const float*)d_in[27];
    const float* Wo_v    = (const float*)d_in[28];
    const float* bo      = (const float*)d_in[29];
    const float* ln_gs   = (const float*)d_in[30];
    const float* ln_bs   = (const float*)d_in[31];
    const float* ln_gv   = (const float*)d_in[32];
    const float* lna_g   = (const float*)d_in[33];
    const float* lna_b   = (const float*)d_in[34];

    float* out      = (float*)d_out;
    float* out_s    = out;
    float* out_v    = out + N_Q*D_F;
    float* out_attn = out + N_Q*D_F*4;

    float* ws = (float*)d_ws;
    float* qs2      = ws;
    float* qv2      = qs2 + N_Q*D_F;
    float* ksc      = qv2 + N_Q*D_F*3;
    float* kvc      = ksc + N_Q*D_F;
    float* skip_s   = kvc + N_Q*D_F*3;
    float* skip_v   = skip_s + N_Q*D_F;
    float* outs_pre = skip_v + N_Q*D_F*3;
    float* outv_pre = outs_pre + N_Q*D_F;
    float* ebuf     = outv_pre + N_Q*D_F*3;       // N*K*512 floats = 134.2 MB

    const size_t base_floats = (size_t)16*N_Q*D_F;
    const size_t ebuf_floats = (size_t)N_Q*K_E*512;
    const bool   use_bulk = ws_size >= (base_floats + ebuf_floats)*sizeof(float);

    hipLaunchKernelGGL(k_qk, dim3(2*N_Q), dim3(D_F), 0, stream,
                       query_s, query_v, key_s, key_v,
                       Wq_s, Wq_v, bq, Wk_s, Wk_v, bk,
                       ln_gs, ln_bs, ln_gv,
                       qs2, qv2, skip_s, skip_v, ksc, kvc);
    if (use_bulk) {
        hipLaunchKernelGGL(k_edge_bulk, dim3(N_Q*K_E/EPB), dim3(512), 0, stream,
                           qs2, qv2, ksc, kvc, eis, eiv, eemb, mask, knn,
                           Wqk_s, Wqk_v, bqk, Wdtp, bdtp,
                           Wagv_s, bagv, Wagv_v, Wattn, lna_g, lna_b,
                           Wval_s, Wval_v, bval,
                           ebuf, out_attn);
        hipLaunchKernelGGL(k_reduce, dim3(N_Q), dim3(D_F), 0, stream,
                           ebuf, out_attn, outs_pre, outv_pre);
    } else {
        hipLaunchKernelGGL(k_edge, dim3(N_Q), dim3(256), 0, stream,
                           qs2, qv2, ksc, kvc, eis, eiv, eemb, mask, knn,
                           Wqk_s, Wqk_v, bqk, Wdtp, bdtp,
                           Wagv_s, bagv, Wagv_v, Wattn, lna_g, lna_b,
                           Wval_s, Wval_v, bval,
                           outs_pre, outv_pre, out_attn);
    }
    hipLaunchKernelGGL(k_out, dim3(N_Q), dim3(D_F), 0, stream,
                       outs_pre, outv_pre, skip_s, skip_v, Wo_s, Wo_v, bo,
                       out_s, out_v);
}

// Round 10
// 4278.478 us; speedup vs baseline: 1.5205x; 1.5205x over previous
//
#include <hip/hip_runtime.h>
#include <hip/hip_bf16.h>
#include <math.h>

#define N_Q 2048
#define K_E 32
#define D_F 128
#define H_N 8
#define DH_N 16
#define EPS_F 1e-5f
#define NEGMAX -3.4028235e38f
#define EPB 8      // edges per E1 block
#define ECON 4     // edges processed concurrently

// dtypes (established): fp32 inputs, int32 mask/knn, FP32 output.
// Round-9 lesson: __launch_bounds__(512,4) VGPR-capped at 64 -> massive scratch
// spill (7 GB writes). Use (512,2): no spill; LDS still allows 2 blocks/CU.

// ---------------------------------------------------------------------------
// Kernel A+B merged: query LN+Wq (blocks [0,N)) and key Wk (blocks [N,2N))
// ---------------------------------------------------------------------------
__global__ __launch_bounds__(128) void k_qk(
    const float* __restrict__ qs_in, const float* __restrict__ qv_in,
    const float* __restrict__ ks_in, const float* __restrict__ kv_in,
    const float* __restrict__ Wq_s, const float* __restrict__ Wq_v, const float* __restrict__ bq,
    const float* __restrict__ Wk_s, const float* __restrict__ Wk_v, const float* __restrict__ bk,
    const float* __restrict__ ln_gs, const float* __restrict__ ln_bs, const float* __restrict__ ln_gv,
    float* __restrict__ qs2, float* __restrict__ qv2,
    float* __restrict__ skip_s, float* __restrict__ skip_v,
    float* __restrict__ ksc, float* __restrict__ kvc)
{
    const int t = threadIdx.x;
    __shared__ float s[D_F], v[D_F*3], sl[D_F], vl[D_F*3];
    if (blockIdx.x < N_Q) {
        const int n = blockIdx.x;
        s[t] = qs_in[n*D_F + t];
        #pragma unroll
        for (int x = 0; x < 3; ++x) v[t*3+x] = qv_in[(n*D_F + t)*3 + x];
        __syncthreads();
        float mu = 0.f;
        for (int i = 0; i < D_F; ++i) mu += s[i];
        mu *= (1.f/D_F);
        float var = 0.f;
        for (int i = 0; i < D_F; ++i) { float d = s[i]-mu; var += d*d; }
        var *= (1.f/D_F);
        float rstd = rsqrtf(var + EPS_F);
        float ssq = 0.f;
        for (int i = 0; i < D_F*3; ++i) ssq += v[i]*v[i];
        float rrms = rsqrtf(ssq*(1.f/D_F) + EPS_F);
        float a = (s[t]-mu)*rstd*ln_gs[t] + ln_bs[t];
        sl[t] = a; skip_s[n*D_F + t] = a;
        float gv = ln_gv[t];
        #pragma unroll
        for (int x = 0; x < 3; ++x) {
            float b = v[t*3+x]*rrms*gv;
            vl[t*3+x] = b; skip_v[(n*D_F + t)*3 + x] = b;
        }
        __syncthreads();
        float acc = bq[t], a0 = 0.f, a1 = 0.f, a2 = 0.f;
        for (int i = 0; i < D_F; ++i) {
            float ws = Wq_s[i*D_F + t]; acc += sl[i]*ws;
            float wv = Wq_v[i*D_F + t];
            a0 += vl[i*3+0]*wv; a1 += vl[i*3+1]*wv; a2 += vl[i*3+2]*wv;
        }
        qs2[n*D_F + t] = acc;
        qv2[(n*D_F + t)*3 + 0] = a0;
        qv2[(n*D_F + t)*3 + 1] = a1;
        qv2[(n*D_F + t)*3 + 2] = a2;
    } else {
        const int n = blockIdx.x - N_Q;
        s[t] = ks_in[n*D_F + t];
        #pragma unroll
        for (int x = 0; x < 3; ++x) v[t*3+x] = kv_in[(n*D_F + t)*3 + x];
        __syncthreads();
        float acc = bk[t], a0 = 0.f, a1 = 0.f, a2 = 0.f;
        for (int i = 0; i < D_F; ++i) {
            float ws = Wk_s[i*D_F + t]; acc += s[i]*ws;
            float wv = Wk_v[i*D_F + t];
            a0 += v[i*3+0]*wv; a1 += v[i*3+1]*wv; a2 += v[i*3+2]*wv;
        }
        ksc[n*D_F + t] = acc;
        kvc[(n*D_F + t)*3 + 0] = a0;
        kvc[(n*D_F + t)*3 + 1] = a1;
        kvc[(n*D_F + t)*3 + 2] = a2;
    }
}

// ---------------------------------------------------------------------------
// E1: bulk edge pipeline. Block = 8 edges (one n), 512 threads, 4 edges
// concurrent. Computes w inline, writes per-edge values to ebuf and raw
// logits to attn buffer. No softmax here (edges fully parallel).
// ---------------------------------------------------------------------------
__global__ __launch_bounds__(512, 2) void k_edge_bulk(
    const float* __restrict__ qs2, const float* __restrict__ qv2,
    const float* __restrict__ ksc, const float* __restrict__ kvc,
    const float* __restrict__ eis, const float* __restrict__ eiv,
    const float* __restrict__ eemb,
    const int* __restrict__ mask, const int* __restrict__ knn,
    const float* __restrict__ Wqk_s, const float* __restrict__ Wqk_v, const float* __restrict__ bqk,
    const float* __restrict__ Wdtp, const float* __restrict__ bdtp,
    const float* __restrict__ Wagv_s, const float* __restrict__ bagv, const float* __restrict__ Wagv_v,
    const float* __restrict__ Wattn, const float* __restrict__ lna_g, const float* __restrict__ lna_b,
    const float* __restrict__ Wval_s, const float* __restrict__ Wval_v, const float* __restrict__ bval,
    float* __restrict__ ebuf, float* __restrict__ attn_raw)
{
    const int t = threadIdx.x;
    const int e0 = blockIdx.x * EPB;
    const int n  = e0 >> 5;
    const int k0 = e0 & 31;
    const int s = t >> 7, c = t & 127, h = (t >> 4) & 7, o = t & 15;

    __shared__ float w_lds[EPB*512];      // 16 KB
    __shared__ float arena[11264];        // 44 KB (ee aliased in stage A)
    __shared__ float sh_qs[D_F], sh_qv[D_F*3];
    __shared__ float sh_es[ECON], sh_ev[ECON*3];

    float* ks_b  = arena;                 // [4][128]
    float* kv_b  = arena + 512;           // [4][384]
    float* cs_b  = arena + 2048;          // [4][256]
    float* cv_b  = arena + 3072;          // [4][768]
    float* ps_b  = arena + 6144;          // [4][128]
    float* pv_b  = arena + 6656;          // [4][384]
    float* agv_b = arena + 8192;          // [4][384]
    float* vv_b  = arena + 9728;          // [4][384]
    float* ee    = arena;                 // [128][8], stage A only

    if (t < D_F) sh_qs[t] = qs2[n*D_F + t];
    if (t < D_F*3 && t >= D_F) sh_qv[t-D_F] = qv2[n*D_F*3 + (t-D_F)];
    { int idx = t + 384; if (idx >= D_F && idx < D_F + D_F*3) sh_qv[idx-D_F] = qv2[n*D_F*3 + (idx-D_F)]; }

    // stage A: ee load (transposed) + w GEMM into LDS
    { int idx = t;       int m = idx & 7, i = idx >> 3; ee[i*EPB+m] = eemb[(size_t)(e0+m)*D_F + i]; }
    { int idx = t + 512; int m = idx & 7, i = idx >> 3; ee[i*EPB+m] = eemb[(size_t)(e0+m)*D_F + i]; }
    __syncthreads();
    {
        float acc[EPB];
        float b = bdtp[t];
        #pragma unroll
        for (int m = 0; m < EPB; ++m) acc[m] = b;
        for (int i = 0; i < D_F; ++i) {
            float wv = Wdtp[i*512 + t];
            #pragma unroll
            for (int m = 0; m < EPB; ++m) acc[m] += ee[i*EPB+m]*wv;
        }
        __syncthreads();              // ee dead -> arena reusable
        #pragma unroll
        for (int m = 0; m < EPB; ++m) w_lds[m*512 + t] = acc[m];
    }

    const float bqk_r  = bqk[o];
    const float bval_r = bval[o];
    const float bag0 = bagv[h*48 + o];
    const float bag1 = bagv[h*48 + 16 + o];
    const float bag2 = bagv[h*48 + 32 + o];
    const int tA = h*32 + o, tB = h*32 + 16 + o;

    for (int p = 0; p < EPB/ECON; ++p) {
        const int m = p*ECON + s;
        const int e = e0 + m;
        // B0: stage k row + edge irreps
        {
            const int j = knn[e];
            ks_b[s*128 + c] = ksc[j*D_F + c];
            #pragma unroll
            for (int r = 0; r < 3; ++r)
                kv_b[s*384 + c + r*128] = kvc[(size_t)j*D_F*3 + c + r*128];
            if (c == 0) {
                sh_es[s] = eis[e];
                sh_ev[s*3+0] = eiv[e*3+0]; sh_ev[s*3+1] = eiv[e*3+1]; sh_ev[s*3+2] = eiv[e*3+2];
            }
        }
        __syncthreads();
        // B1: dtp1
        {
            float s1 = sh_qs[c], kd = ks_b[s*128+c];
            float q0 = sh_qv[c*3+0], q1 = sh_qv[c*3+1], q2 = sh_qv[c*3+2];
            float k0v = kv_b[s*384 + c*3+0], k1v = kv_b[s*384 + c*3+1], k2v = kv_b[s*384 + c*3+2];
            cs_b[s*256 + c]       = s1*kd;
            cs_b[s*256 + 128 + c] = q0*k0v + q1*k1v + q2*k2v;
            cv_b[s*768 + c*3+0] = s1*k0v; cv_b[s*768 + c*3+1] = s1*k1v; cv_b[s*768 + c*3+2] = s1*k2v;
            cv_b[s*768 + (128+c)*3+0] = kd*q0; cv_b[s*768 + (128+c)*3+1] = kd*q1; cv_b[s*768 + (128+c)*3+2] = kd*q2;
        }
        __syncthreads();
        // B2: Wqk
        {
            float as = bqk_r, av0=0.f, av1=0.f, av2=0.f;
            for (int ii = 0; ii < 32; ++ii) {
                int i = (ii + h*8) & 31;
                int cb = h*32 + i;
                float ws = Wqk_s[i*16 + o];
                as += cs_b[s*256 + cb]*ws;
                float wv = Wqk_v[i*16 + o];
                av0 += cv_b[s*768 + cb*3+0]*wv;
                av1 += cv_b[s*768 + cb*3+1]*wv;
                av2 += cv_b[s*768 + cb*3+2]*wv;
            }
            ps_b[s*128 + c] = as;
            pv_b[s*384 + c*3+0] = av0; pv_b[s*384 + c*3+1] = av1; pv_b[s*384 + c*3+2] = av2;
        }
        __syncthreads();
        // B3: dtp2 (weighted)
        {
            const float* wm = &w_lds[m*512];
            float es = sh_es[s];
            float evx = sh_ev[s*3+0], evy = sh_ev[s*3+1], evz = sh_ev[s*3+2];
            float s1 = ps_b[s*128 + c];
            float w0 = wm[c], w1 = wm[128+c], w2 = wm[256+c], w3 = wm[384+c];
            cs_b[s*256 + tA] = s1*es*w0;
            cv_b[s*768 + tA*3+0] = s1*evx*w2; cv_b[s*768 + tA*3+1] = s1*evy*w2; cv_b[s*768 + tA*3+2] = s1*evz*w2;
            float p0 = pv_b[s*384 + c*3+0], p1 = pv_b[s*384 + c*3+1], p2 = pv_b[s*384 + c*3+2];
            cs_b[s*256 + tB] = (p0*evx + p1*evy + p2*evz)*w1;
            cv_b[s*768 + tB*3+0] = es*p0*w3; cv_b[s*768 + tB*3+1] = es*p1*w3; cv_b[s*768 + tB*3+2] = es*p2*w3;
        }
        __syncthreads();
        // B4: Wagv
        {
            float aatt = bag0, agate = bag1, avals = bag2;
            float v0=0.f, v1=0.f, v2=0.f;
            for (int ii = 0; ii < 32; ++ii) {
                int i = (ii + h*8) & 31;
                int cb = h*32 + i;
                float a_s = cs_b[s*256 + cb];
                const float* wrow = &Wagv_s[(h*32+i)*48];
                aatt  += a_s*wrow[o];
                agate += a_s*wrow[16+o];
                avals += a_s*wrow[32+o];
                float wv = Wagv_v[(h*32+i)*16 + o];
                v0 += cv_b[s*768 + cb*3+0]*wv;
                v1 += cv_b[s*768 + cb*3+1]*wv;
                v2 += cv_b[s*768 + cb*3+2]*wv;
            }
            agv_b[s*384 + h*48 + o]      = aatt;
            agv_b[s*384 + h*48 + 16 + o] = agate;
            agv_b[s*384 + h*48 + 32 + o] = avals;
            vv_b[s*384 + c*3+0] = v0; vv_b[s*384 + c*3+1] = v1; vv_b[s*384 + c*3+2] = v2;
        }
        __syncthreads();
        // B5: logit (t<32 -> 4 edges x 8 heads) + gating (all threads)
        if (t < ECON*H_N) {
            int s2 = t >> 3, h2 = t & 7;
            const float* af = &agv_b[s2*384 + h2*48];
            float mu = 0.f;
            for (int d2 = 0; d2 < DH_N; ++d2) mu += af[d2];
            mu *= (1.f/DH_N);
            float var = 0.f;
            for (int d2 = 0; d2 < DH_N; ++d2) { float dd = af[d2]-mu; var += dd*dd; }
            var *= (1.f/DH_N);
            float rstd = rsqrtf(var + EPS_F);
            float logit = 0.f;
            for (int d2 = 0; d2 < DH_N; ++d2) {
                float xn = (af[d2]-mu)*rstd*lna_g[d2] + lna_b[d2];
                logit += xn*Wattn[d2];
            }
            int e2 = e0 + p*ECON + s2;
            if (mask[e2] == 0) logit = NEGMAX;
            attn_raw[h2*(N_Q*K_E) + n*K_E + (k0 + p*ECON + s2)] = logit;
        }
        {
            float vraw = agv_b[s*384 + h*48 + 32 + o];
            float sact = vraw / (1.f + expf(-vraw));
            float g = 1.f / (1.f + expf(-agv_b[s*384 + h*48 + 16 + o]));
            ps_b[s*128 + c] = sact;
            pv_b[s*384 + c*3+0] = vv_b[s*384 + c*3+0]*g;
            pv_b[s*384 + c*3+1] = vv_b[s*384 + c*3+1]*g;
            pv_b[s*384 + c*3+2] = vv_b[s*384 + c*3+2]*g;
        }
        __syncthreads();
        // B6: dtp3
        {
            float es = sh_es[s];
            float evx = sh_ev[s*3+0], evy = sh_ev[s*3+1], evz = sh_ev[s*3+2];
            float s1 = ps_b[s*128 + c];
            cs_b[s*256 + tA] = s1*es;
            cv_b[s*768 + tA*3+0] = s1*evx; cv_b[s*768 + tA*3+1] = s1*evy; cv_b[s*768 + tA*3+2] = s1*evz;
            float p0 = pv_b[s*384 + c*3+0], p1 = pv_b[s*384 + c*3+1], p2 = pv_b[s*384 + c*3+2];
            cs_b[s*256 + tB] = p0*evx + p1*evy + p2*evz;
            cv_b[s*768 + tB*3+0] = es*p0; cv_b[s*768 + tB*3+1] = es*p1; cv_b[s*768 + tB*3+2] = es*p2;
        }
        __syncthreads();
        // B7: Wval -> ebuf
        {
            float vs = bval_r, v0=0.f, v1=0.f, v2=0.f;
            for (int ii = 0; ii < 32; ++ii) {
                int i = (ii + h*8) & 31;
                int cb = h*32 + i;
                float ws = Wval_s[i*16 + o];
                vs += cs_b[s*256 + cb]*ws;
                float wv = Wval_v[i*16 + o];
                v0 += cv_b[s*768 + cb*3+0]*wv;
                v1 += cv_b[s*768 + cb*3+1]*wv;
                v2 += cv_b[s*768 + cb*3+2]*wv;
            }
            float* eb = &ebuf[(size_t)e*512];
            eb[c] = vs;
            eb[128 + c*3+0] = v0; eb[128 + c*3+1] = v1; eb[128 + c*3+2] = v2;
        }
        __syncthreads();
    }
}

// ---------------------------------------------------------------------------
// E2: per-n softmax (raw logits in attn buffer) + attention-weighted sum
// ---------------------------------------------------------------------------
__global__ __launch_bounds__(128) void k_reduce(
    const float* __restrict__ ebuf,
    float* __restrict__ attn_out,     // in: raw logits, out: probabilities
    float* __restrict__ outs_pre, float* __restrict__ outv_pre)
{
    const int n = blockIdx.x, t = threadIdx.x;
    __shared__ float sh_attn[H_N*K_E];
    if (t < H_N) {
        float lg[K_E];
        float mx = NEGMAX;
        for (int k = 0; k < K_E; ++k) {
            lg[k] = attn_out[t*(N_Q*K_E) + n*K_E + k];
            mx = fmaxf(mx, lg[k]);
        }
        float sum = 0.f;
        for (int k = 0; k < K_E; ++k) { float p = expf(lg[k]-mx); lg[k] = p; sum += p; }
        float rinv = 1.f/sum;
        for (int k = 0; k < K_E; ++k) {
            float a = lg[k]*rinv;
            sh_attn[t*K_E + k] = a;
            attn_out[t*(N_Q*K_E) + n*K_E + k] = a;
        }
    }
    __syncthreads();
    const int h = t >> 4;
    float accs = 0.f, a0 = 0.f, a1 = 0.f, a2 = 0.f;
    for (int k = 0; k < K_E; ++k) {
        float a = sh_attn[h*K_E + k];
        const float* eb = &ebuf[(size_t)(n*K_E + k)*512];
        accs += a*eb[t];
        a0 += a*eb[128 + t*3+0];
        a1 += a*eb[128 + t*3+1];
        a2 += a*eb[128 + t*3+2];
    }
    outs_pre[n*D_F + t] = accs;
    outv_pre[(n*D_F+t)*3+0] = a0;
    outv_pre[(n*D_F+t)*3+1] = a1;
    outv_pre[(n*D_F+t)*3+2] = a2;
}

// ---------------------------------------------------------------------------
// Fallback (round-7 monolithic, needs only 16*N*D scratch)
// ---------------------------------------------------------------------------
__global__ __launch_bounds__(256) void k_edge(
    const float* __restrict__ qs2, const float* __restrict__ qv2,
    const float* __restrict__ ksc, const float* __restrict__ kvc,
    const float* __restrict__ eis, const float* __restrict__ eiv,
    const float* __restrict__ eemb,
    const int* __restrict__ mask, const int* __restrict__ knn,
    const float* __restrict__ Wqk_s, const float* __restrict__ Wqk_v, const float* __restrict__ bqk,
    const float* __restrict__ Wdtp, const float* __restrict__ bdtp,
    const float* __restrict__ Wagv_s, const float* __restrict__ bagv, const float* __restrict__ Wagv_v,
    const float* __restrict__ Wattn, const float* __restrict__ lna_g, const float* __restrict__ lna_b,
    const float* __restrict__ Wval_s, const float* __restrict__ Wval_v, const float* __restrict__ bval,
    float* __restrict__ outs_pre, float* __restrict__ outv_pre,
    float* __restrict__ attn_out)
{
    const int n = blockIdx.x, t = threadIdx.x;
    __shared__ float sh_qs[D_F], sh_qv[D_F*3];
    __shared__ float sh_ks[D_F], sh_kv[D_F*3], sh_ee[D_F];
    __shared__ float sh_cs[2*D_F], sh_cv[2*D_F*3];
    __shared__ float sh_ps[D_F], sh_pv[D_F*3];
    __shared__ float sh_w[4*D_F];
    __shared__ float sh_agv[H_N*48], sh_valv[H_N*DH_N*3];
    __shared__ float sh_logit[H_N*K_E], sh_red[H_N*2];
    __shared__ float sh_es, sh_ev[3];
    float m_run = NEGMAX, l_run = 0.f;
    float accs = 0.f, acc0 = 0.f, acc1 = 0.f, acc2 = 0.f;
    if (t < D_F) sh_qs[t] = qs2[n*D_F + t];
    for (int idx = t; idx < D_F*3; idx += 256) sh_qv[idx] = qv2[n*D_F*3 + idx];
    for (int k = 0; k < K_E; ++k) {
        const int e = n*K_E + k;
        const int j = knn[e];
        if (t < D_F) { sh_ks[t] = ksc[j*D_F + t]; sh_ee[t] = eemb[e*D_F + t]; }
        for (int idx = t; idx < D_F*3; idx += 256) sh_kv[idx] = kvc[j*D_F*3 + idx];
        if (t == 0) {
            sh_es = eis[e];
            sh_ev[0] = eiv[e*3+0]; sh_ev[1] = eiv[e*3+1]; sh_ev[2] = eiv[e*3+2];
        }
        __syncthreads();
        {
            const int c = t;
            if (c < D_F) {
                float s1 = sh_qs[c];
                sh_cs[c] = s1 * sh_ks[c];
                #pragma unroll
                for (int x = 0; x < 3; ++x) sh_cv[c*3+x] = s1 * sh_kv[c*3+x];
            } else {
                int d = c - D_F;
                float dot = 0.f;
                #pragma unroll
                for (int x = 0; x < 3; ++x) dot += sh_qv[d*3+x]*sh_kv[d*3+x];
                sh_cs[c] = dot;
                #pragma unroll
                for (int x = 0; x < 3; ++x) sh_cv[c*3+x] = sh_ks[d]*sh_qv[d*3+x];
            }
        }
        __syncthreads();
        #pragma unroll
        for (int r = 0; r < 2; ++r) {
            int oo = t + r*256;
            float acc = bdtp[oo];
            for (int i = 0; i < D_F; ++i) acc += sh_ee[i]*Wdtp[i*512 + oo];
            sh_w[oo] = acc;
        }
        if (t < D_F) {
            int h = t >> 4, o = t & 15;
            float as = bqk[o], av0 = 0.f, av1 = 0.f, av2 = 0.f;
            for (int i = 0; i < 32; ++i) {
                int cb = h*32 + i;
                float ws = Wqk_s[i*16 + o];
                as += sh_cs[cb]*ws;
                float wv = Wqk_v[i*16 + o];
                av0 += sh_cv[cb*3+0]*wv; av1 += sh_cv[cb*3+1]*wv; av2 += sh_cv[cb*3+2]*wv;
            }
            sh_ps[t] = as;
            sh_pv[t*3+0] = av0; sh_pv[t*3+1] = av1; sh_pv[t*3+2] = av2;
        }
        __syncthreads();
        {
            int h = t >> 5, i = t & 31;
            float es = sh_es;
            if (i < DH_N) {
                int cc = h*DH_N + i;
                float s1 = sh_ps[cc];
                sh_cs[t] = s1*es*sh_w[0*D_F + cc];
                float w2 = sh_w[2*D_F + cc];
                #pragma unroll
                for (int x = 0; x < 3; ++x) sh_cv[t*3+x] = s1*sh_ev[x]*w2;
            } else {
                int cc = h*DH_N + (i - DH_N);
                float dot = 0.f;
                #pragma unroll
                for (int x = 0; x < 3; ++x) dot += sh_pv[cc*3+x]*sh_ev[x];
                sh_cs[t] = dot*sh_w[1*D_F + cc];
                float w3 = sh_w[3*D_F + cc];
                #pragma unroll
                for (int x = 0; x < 3; ++x) sh_cv[t*3+x] = es*sh_pv[cc*3+x]*w3;
            }
        }
        __syncthreads();
        for (int idx = t; idx < H_N*48; idx += 256) {
            int h = idx / 48, oo = idx % 48;
            float acc = bagv[h*48 + oo];
            for (int i = 0; i < 32; ++i)
                acc += sh_cs[h*32 + i]*Wagv_s[(h*32 + i)*48 + oo];
            sh_agv[idx] = acc;
        }
        if (t < D_F) {
            int h = t >> 4, o = t & 15;
            float a0 = 0.f, a1 = 0.f, a2 = 0.f;
            for (int i = 0; i < 32; ++i) {
                float wv = Wagv_v[(h*32 + i)*16 + o];
                a0 += sh_cv[(h*32+i)*3+0]*wv;
                a1 += sh_cv[(h*32+i)*3+1]*wv;
                a2 += sh_cv[(h*32+i)*3+2]*wv;
            }
            sh_valv[t*3+0] = a0; sh_valv[t*3+1] = a1; sh_valv[t*3+2] = a2;
        }
        __syncthreads();
        if (t < H_N) {
            const float* af = &sh_agv[t*48];
            float mu = 0.f;
            for (int d2 = 0; d2 < DH_N; ++d2) mu += af[d2];
            mu *= (1.f/DH_N);
            float var = 0.f;
            for (int d2 = 0; d2 < DH_N; ++d2) { float dd = af[d2]-mu; var += dd*dd; }
            var *= (1.f/DH_N);
            float rstd = rsqrtf(var + EPS_F);
            float logit = 0.f;
            for (int d2 = 0; d2 < DH_N; ++d2) {
                float xn = (af[d2]-mu)*rstd*lna_g[d2] + lna_b[d2];
                logit += xn*Wattn[d2];
            }
            if (mask[e] == 0) logit = NEGMAX;
            sh_logit[t*K_E + k] = logit;
            float m_new = fmaxf(m_run, logit);
            float alpha = expf(m_run - m_new);
            float p     = expf(logit - m_new);
            l_run = l_run*alpha + p;
            m_run = m_new;
            sh_red[t*2]   = alpha;
            sh_red[t*2+1] = p;
        }
        if (t < D_F) {
            int h = t >> 4, o = t & 15;
            float vraw = sh_agv[h*48 + 32 + o];
            float sact = vraw / (1.f + expf(-vraw));
            float g = 1.f / (1.f + expf(-sh_agv[h*48 + 16 + o]));
            sh_ps[t] = sact;
            #pragma unroll
            for (int x = 0; x < 3; ++x) sh_pv[t*3+x] = sh_valv[t*3+x]*g;
        }
        __syncthreads();
        {
            int h = t >> 5, i = t & 31;
            if (i < DH_N) {
                int cc = h*DH_N + i;
                float s1 = sh_ps[cc];
                sh_cs[t] = s1*sh_es;
                #pragma unroll
                for (int x = 0; x < 3; ++x) sh_cv[t*3+x] = s1*sh_ev[x];
            } else {
                int cc = h*DH_N + (i - DH_N);
                float dot = 0.f;
                #pragma unroll
                for (int x = 0; x < 3; ++x) dot += sh_pv[cc*3+x]*sh_ev[x];
                sh_cs[t] = dot;
                #pragma unroll
                for (int x = 0; x < 3; ++x) sh_cv[t*3+x] = sh_es*sh_pv[cc*3+x];
            }
        }
        __syncthreads();
        if (t < D_F) {
            int h = t >> 4, o = t & 15;
            float vs = bval[o], v0 = 0.f, v1 = 0.f, v2 = 0.f;
            for (int i = 0; i < 32; ++i) {
                int cb = h*32 + i;
                float ws = Wval_s[i*16 + o];
                vs += sh_cs[cb]*ws;
                float wv = Wval_v[i*16 + o];
                v0 += sh_cv[cb*3+0]*wv; v1 += sh_cv[cb*3+1]*wv; v2 += sh_cv[cb*3+2]*wv;
            }
            float alpha = sh_red[h*2], p = sh_red[h*2+1];
            accs = accs*alpha + p*vs;
            acc0 = acc0*alpha + p*v0;
            acc1 = acc1*alpha + p*v1;
            acc2 = acc2*alpha + p*v2;
        }
        __syncthreads();
    }
    if (t < H_N) {
        sh_red[t*2]   = m_run;
        sh_red[t*2+1] = 1.f / l_run;
    }
    __syncthreads();
    {
        int h = t >> 5, k = t & 31;
        float a = expf(sh_logit[t] - sh_red[h*2]) * sh_red[h*2+1];
        attn_out[h*(N_Q*K_E) + n*K_E + k] = a;
    }
    if (t < D_F) {
        int h = t >> 4;
        float rinv = sh_red[h*2+1];
        outs_pre[n*D_F + t]     = accs*rinv;
        outv_pre[(n*D_F+t)*3+0] = acc0*rinv;
        outv_pre[(n*D_F+t)*3+1] = acc1*rinv;
        outv_pre[(n*D_F+t)*3+2] = acc2*rinv;
    }
}

// ---------------------------------------------------------------------------
// Kernel D: output eq_linear(Wo) + skip add
// ---------------------------------------------------------------------------
__global__ __launch_bounds__(128) void k_out(
    const float* __restrict__ outs_pre, const float* __restrict__ outv_pre,
    const float* __restrict__ skip_s, const float* __restrict__ skip_v,
    const float* __restrict__ Wo_s, const float* __restrict__ Wo_v, const float* __restrict__ bo,
    float* __restrict__ out0, float* __restrict__ out1)
{
    const int n = blockIdx.x, t = threadIdx.x;
    __shared__ float ps[D_F], pv[D_F*3];
    ps[t] = outs_pre[n*D_F + t];
    #pragma unroll
    for (int x = 0; x < 3; ++x) pv[t*3+x] = outv_pre[(n*D_F + t)*3 + x];
    __syncthreads();
    float acc = bo[t], a0 = 0.f, a1 = 0.f, a2 = 0.f;
    for (int i = 0; i < D_F; ++i) {
        float ws = Wo_s[i*D_F + t]; acc += ps[i]*ws;
        float wv = Wo_v[i*D_F + t];
        a0 += pv[i*3+0]*wv; a1 += pv[i*3+1]*wv; a2 += pv[i*3+2]*wv;
    }
    out0[n*D_F + t] = acc + skip_s[n*D_F + t];
    out1[(n*D_F + t)*3 + 0] = a0 + skip_v[(n*D_F + t)*3 + 0];
    out1[(n*D_F + t)*3 + 1] = a1 + skip_v[(n*D_F + t)*3 + 1];
    out1[(n*D_F + t)*3 + 2] = a2 + skip_v[(n*D_F + t)*3 + 2];
}

// ---------------------------------------------------------------------------
extern "C" void kernel_launch(void* const* d_in, const int* in_sizes, int n_in,
                              void* d_out, int out_size, void* d_ws, size_t ws_size,
                              hipStream_t stream)
{
    (void)in_sizes; (void)n_in; (void)out_size;

    const float* query_s = (const float*)d_in[0];
    const float* query_v = (const float*)d_in[1];
    const float* key_s   = (const float*)d_in[2];
    const float* key_v   = (const float*)d_in[3];
    const float* eis     = (const float*)d_in[4];
    const float* eiv     = (const float*)d_in[5];
    const float* eemb    = (const float*)d_in[6];
    const int*   mask    = (const int*)d_in[7];
    const int*   knn     = (const int*)d_in[8];
    const float* Wq_s    = (const float*)d_in[9];
    const float* Wq_v    = (const float*)d_in[10];
    const float* bq      = (const float*)d_in[11];
    const float* Wk_s    = (const float*)d_in[12];
    const float* Wk_v    = (const float*)d_in[13];
    const float* bk      = (const float*)d_in[14];
    const float* Wqk_s   = (const float*)d_in[15];
    const float* Wqk_v   = (const float*)d_in[16];
    const float* bqk     = (const float*)d_in[17];
    const float* Wdtp    = (const float*)d_in[18];
    const float* bdtp    = (const float*)d_in[19];
    const float* Wagv_s  = (const float*)d_in[20];
    const float* bagv    = (const float*)d_in[21];
    const float* Wagv_v  = (const float*)d_in[22];
    const float* Wattn   = (const float*)d_in[23];
    const float* Wval_s  = (const float*)d_in[24];
    const float* Wval_v  = (const float*)d_in[25];
    const float* bval    = (const float*)d_in[26];
    const float* Wo_s    = (const float*)d_in[27];
    const float* Wo_v    = (const float*)d_in[28];
    const float* bo      = (const float*)d_in[29];
    const float* ln_gs   = (const float*)d_in[30];
    const float* ln_bs   = (const float*)d_in[31];
    const float* ln_gv   = (const float*)d_in[32];
    const float* lna_g   = (const float*)d_in[33];
    const float* lna_b   = (const float*)d_in[34];

    float* out      = (float*)d_out;
    float* out_s    = out;
    float* out_v    = out + N_Q*D_F;
    float* out_attn = out + N_Q*D_F*4;

    float* ws = (float*)d_ws;
    float* qs2      = ws;
    float* qv2      = qs2 + N_Q*D_F;
    float* ksc      = qv2 + N_Q*D_F*3;
    float* kvc      = ksc + N_Q*D_F;
    float* skip_s   = kvc + N_Q*D_F*3;
    float* skip_v   = skip_s + N_Q*D_F;
    float* outs_pre = skip_v + N_Q*D_F*3;
    float* outv_pre = outs_pre + N_Q*D_F;
    float* ebuf     = outv_pre + N_Q*D_F*3;       // N*K*512 floats = 134.2 MB

    const size_t base_floats = (size_t)16*N_Q*D_F;
    const size_t ebuf_floats = (size_t)N_Q*K_E*512;
    const bool   use_bulk = ws_size >= (base_floats + ebuf_floats)*sizeof(float);

    hipLaunchKernelGGL(k_qk, dim3(2*N_Q), dim3(D_F), 0, stream,
                       query_s, query_v, key_s, key_v,
                       Wq_s, Wq_v, bq, Wk_s, Wk_v, bk,
                       ln_gs, ln_bs, ln_gv,
                       qs2, qv2, skip_s, skip_v, ksc, kvc);
    if (use_bulk) {
        hipLaunchKernelGGL(k_edge_bulk, dim3(N_Q*K_E/EPB), dim3(512), 0, stream,
                           qs2, qv2, ksc, kvc, eis, eiv, eemb, mask, knn,
                           Wqk_s, Wqk_v, bqk, Wdtp, bdtp,
                           Wagv_s, bagv, Wagv_v, Wattn, lna_g, lna_b,
                           Wval_s, Wval_v, bval,
                           ebuf, out_attn);
        hipLaunchKernelGGL(k_reduce, dim3(N_Q), dim3(D_F), 0, stream,
                           ebuf, out_attn, outs_pre, outv_pre);
    } else {
        hipLaunchKernelGGL(k_edge, dim3(N_Q), dim3(256), 0, stream,
                           qs2, qv2, ksc, kvc, eis, eiv, eemb, mask, knn,
                           Wqk_s, Wqk_v, bqk, Wdtp, bdtp,
                           Wagv_s, bagv, Wagv_v, Wattn, lna_g, lna_b,
                           Wval_s, Wval_v, bval,
                           outs_pre, outv_pre, out_attn);
    }
    hipLaunchKernelGGL(k_out, dim3(N_Q), dim3(D_F), 0, stream,
                       outs_pre, outv_pre, skip_s, skip_v, Wo_s, Wo_v, bo,
                       out_s, out_v);
}

// Round 11
// 754.338 us; speedup vs baseline: 8.6240x; 5.6718x over previous
//
#include <hip/hip_runtime.h>
#include <hip/hip_bf16.h>
#include <math.h>

#define N_Q 2048
#define K_E 32
#define D_F 128
#define H_N 8
#define DH_N 16
#define EPS_F 1e-5f
#define NEGMAX -3.4028235e38f
#define EPB 8      // edges per E1 block
#define ECON 4     // edges processed concurrently

// dtypes (established): fp32 inputs, int32 mask/knn, FP32 output.
// Round-9/10 lesson: any forced min-occupancy in __launch_bounds__ VGPR-caps
// the kernel below its natural demand -> multi-GB scratch spill. Leave the
// cap at the hardware 256 (8-wave block) and tame unrolling instead.

// ---------------------------------------------------------------------------
// Kernel A+B merged: query LN+Wq (blocks [0,N)) and key Wk (blocks [N,2N))
// ---------------------------------------------------------------------------
__global__ __launch_bounds__(128) void k_qk(
    const float* __restrict__ qs_in, const float* __restrict__ qv_in,
    const float* __restrict__ ks_in, const float* __restrict__ kv_in,
    const float* __restrict__ Wq_s, const float* __restrict__ Wq_v, const float* __restrict__ bq,
    const float* __restrict__ Wk_s, const float* __restrict__ Wk_v, const float* __restrict__ bk,
    const float* __restrict__ ln_gs, const float* __restrict__ ln_bs, const float* __restrict__ ln_gv,
    float* __restrict__ qs2, float* __restrict__ qv2,
    float* __restrict__ skip_s, float* __restrict__ skip_v,
    float* __restrict__ ksc, float* __restrict__ kvc)
{
    const int t = threadIdx.x;
    __shared__ float s[D_F], v[D_F*3], sl[D_F], vl[D_F*3];
    if (blockIdx.x < N_Q) {
        const int n = blockIdx.x;
        s[t] = qs_in[n*D_F + t];
        #pragma unroll
        for (int x = 0; x < 3; ++x) v[t*3+x] = qv_in[(n*D_F + t)*3 + x];
        __syncthreads();
        float mu = 0.f;
        for (int i = 0; i < D_F; ++i) mu += s[i];
        mu *= (1.f/D_F);
        float var = 0.f;
        for (int i = 0; i < D_F; ++i) { float d = s[i]-mu; var += d*d; }
        var *= (1.f/D_F);
        float rstd = rsqrtf(var + EPS_F);
        float ssq = 0.f;
        for (int i = 0; i < D_F*3; ++i) ssq += v[i]*v[i];
        float rrms = rsqrtf(ssq*(1.f/D_F) + EPS_F);
        float a = (s[t]-mu)*rstd*ln_gs[t] + ln_bs[t];
        sl[t] = a; skip_s[n*D_F + t] = a;
        float gv = ln_gv[t];
        #pragma unroll
        for (int x = 0; x < 3; ++x) {
            float b = v[t*3+x]*rrms*gv;
            vl[t*3+x] = b; skip_v[(n*D_F + t)*3 + x] = b;
        }
        __syncthreads();
        float acc = bq[t], a0 = 0.f, a1 = 0.f, a2 = 0.f;
        for (int i = 0; i < D_F; ++i) {
            float ws = Wq_s[i*D_F + t]; acc += sl[i]*ws;
            float wv = Wq_v[i*D_F + t];
            a0 += vl[i*3+0]*wv; a1 += vl[i*3+1]*wv; a2 += vl[i*3+2]*wv;
        }
        qs2[n*D_F + t] = acc;
        qv2[(n*D_F + t)*3 + 0] = a0;
        qv2[(n*D_F + t)*3 + 1] = a1;
        qv2[(n*D_F + t)*3 + 2] = a2;
    } else {
        const int n = blockIdx.x - N_Q;
        s[t] = ks_in[n*D_F + t];
        #pragma unroll
        for (int x = 0; x < 3; ++x) v[t*3+x] = kv_in[(n*D_F + t)*3 + x];
        __syncthreads();
        float acc = bk[t], a0 = 0.f, a1 = 0.f, a2 = 0.f;
        for (int i = 0; i < D_F; ++i) {
            float ws = Wk_s[i*D_F + t]; acc += s[i]*ws;
            float wv = Wk_v[i*D_F + t];
            a0 += v[i*3+0]*wv; a1 += v[i*3+1]*wv; a2 += v[i*3+2]*wv;
        }
        ksc[n*D_F + t] = acc;
        kvc[(n*D_F + t)*3 + 0] = a0;
        kvc[(n*D_F + t)*3 + 1] = a1;
        kvc[(n*D_F + t)*3 + 2] = a2;
    }
}

// ---------------------------------------------------------------------------
// E1: bulk edge pipeline. Block = 8 edges (one n), 512 threads, 4 edges
// concurrent. w computed inline into LDS; per-edge values to ebuf; raw
// logits to attn buffer. Unroll pragmas keep VGPR demand under the 256 cap.
// ---------------------------------------------------------------------------
__global__ __launch_bounds__(512) void k_edge_bulk(
    const float* __restrict__ qs2, const float* __restrict__ qv2,
    const float* __restrict__ ksc, const float* __restrict__ kvc,
    const float* __restrict__ eis, const float* __restrict__ eiv,
    const float* __restrict__ eemb,
    const int* __restrict__ mask, const int* __restrict__ knn,
    const float* __restrict__ Wqk_s, const float* __restrict__ Wqk_v, const float* __restrict__ bqk,
    const float* __restrict__ Wdtp, const float* __restrict__ bdtp,
    const float* __restrict__ Wagv_s, const float* __restrict__ bagv, const float* __restrict__ Wagv_v,
    const float* __restrict__ Wattn, const float* __restrict__ lna_g, const float* __restrict__ lna_b,
    const float* __restrict__ Wval_s, const float* __restrict__ Wval_v, const float* __restrict__ bval,
    float* __restrict__ ebuf, float* __restrict__ attn_raw)
{
    const int t = threadIdx.x;
    const int e0 = blockIdx.x * EPB;
    const int n  = e0 >> 5;
    const int k0 = e0 & 31;
    const int s = t >> 7, c = t & 127, h = (t >> 4) & 7, o = t & 15;

    __shared__ float w_lds[EPB*512];      // 16 KB
    __shared__ float arena[11264];        // 44 KB (ee aliased in stage A)
    __shared__ float sh_qs[D_F], sh_qv[D_F*3];
    __shared__ float sh_es[ECON], sh_ev[ECON*3];

    float* ks_b  = arena;                 // [4][128]
    float* kv_b  = arena + 512;           // [4][384]
    float* cs_b  = arena + 2048;          // [4][256]
    float* cv_b  = arena + 3072;          // [4][768]
    float* ps_b  = arena + 6144;          // [4][128]
    float* pv_b  = arena + 6656;          // [4][384]
    float* agv_b = arena + 8192;          // [4][384]
    float* vv_b  = arena + 9728;          // [4][384]
    float* ee    = arena;                 // [128][8], stage A only

    if (t < D_F) sh_qs[t] = qs2[n*D_F + t];
    if (t < D_F*3 && t >= D_F) sh_qv[t-D_F] = qv2[n*D_F*3 + (t-D_F)];
    { int idx = t + 384; if (idx >= D_F && idx < D_F + D_F*3) sh_qv[idx-D_F] = qv2[n*D_F*3 + (idx-D_F)]; }

    // stage A: ee load (transposed) + w GEMM into LDS
    { int idx = t;       int m = idx & 7, i = idx >> 3; ee[i*EPB+m] = eemb[(size_t)(e0+m)*D_F + i]; }
    { int idx = t + 512; int m = idx & 7, i = idx >> 3; ee[i*EPB+m] = eemb[(size_t)(e0+m)*D_F + i]; }
    __syncthreads();
    {
        float acc[EPB];
        float b = bdtp[t];
        #pragma unroll
        for (int m = 0; m < EPB; ++m) acc[m] = b;
        #pragma unroll 2
        for (int i = 0; i < D_F; ++i) {
            float wv = Wdtp[i*512 + t];
            #pragma unroll
            for (int m = 0; m < EPB; ++m) acc[m] += ee[i*EPB+m]*wv;
        }
        __syncthreads();              // ee dead -> arena reusable
        #pragma unroll
        for (int m = 0; m < EPB; ++m) w_lds[m*512 + t] = acc[m];
    }

    const float bqk_r  = bqk[o];
    const float bval_r = bval[o];
    const float bag0 = bagv[h*48 + o];
    const float bag1 = bagv[h*48 + 16 + o];
    const float bag2 = bagv[h*48 + 32 + o];
    const int tA = h*32 + o, tB = h*32 + 16 + o;

    for (int p = 0; p < EPB/ECON; ++p) {
        const int m = p*ECON + s;
        const int e = e0 + m;
        // B0: stage k row + edge irreps
        {
            const int j = knn[e];
            ks_b[s*128 + c] = ksc[j*D_F + c];
            #pragma unroll
            for (int r = 0; r < 3; ++r)
                kv_b[s*384 + c + r*128] = kvc[(size_t)j*D_F*3 + c + r*128];
            if (c == 0) {
                sh_es[s] = eis[e];
                sh_ev[s*3+0] = eiv[e*3+0]; sh_ev[s*3+1] = eiv[e*3+1]; sh_ev[s*3+2] = eiv[e*3+2];
            }
        }
        __syncthreads();
        // B1: dtp1
        {
            float s1 = sh_qs[c], kd = ks_b[s*128+c];
            float q0 = sh_qv[c*3+0], q1 = sh_qv[c*3+1], q2 = sh_qv[c*3+2];
            float k0v = kv_b[s*384 + c*3+0], k1v = kv_b[s*384 + c*3+1], k2v = kv_b[s*384 + c*3+2];
            cs_b[s*256 + c]       = s1*kd;
            cs_b[s*256 + 128 + c] = q0*k0v + q1*k1v + q2*k2v;
            cv_b[s*768 + c*3+0] = s1*k0v; cv_b[s*768 + c*3+1] = s1*k1v; cv_b[s*768 + c*3+2] = s1*k2v;
            cv_b[s*768 + (128+c)*3+0] = kd*q0; cv_b[s*768 + (128+c)*3+1] = kd*q1; cv_b[s*768 + (128+c)*3+2] = kd*q2;
        }
        __syncthreads();
        // B2: Wqk (unroll-limited: 4 global loads/iter would explode VGPRs)
        {
            float as = bqk_r, av0=0.f, av1=0.f, av2=0.f;
            #pragma unroll 4
            for (int ii = 0; ii < 32; ++ii) {
                int i = (ii + h*8) & 31;
                int cb = h*32 + i;
                float ws = Wqk_s[i*16 + o];
                as += cs_b[s*256 + cb]*ws;
                float wv = Wqk_v[i*16 + o];
                av0 += cv_b[s*768 + cb*3+0]*wv;
                av1 += cv_b[s*768 + cb*3+1]*wv;
                av2 += cv_b[s*768 + cb*3+2]*wv;
            }
            ps_b[s*128 + c] = as;
            pv_b[s*384 + c*3+0] = av0; pv_b[s*384 + c*3+1] = av1; pv_b[s*384 + c*3+2] = av2;
        }
        __syncthreads();
        // B3: dtp2 (weighted)
        {
            const float* wm = &w_lds[m*512];
            float es = sh_es[s];
            float evx = sh_ev[s*3+0], evy = sh_ev[s*3+1], evz = sh_ev[s*3+2];
            float s1 = ps_b[s*128 + c];
            float w0 = wm[c], w1 = wm[128+c], w2 = wm[256+c], w3 = wm[384+c];
            cs_b[s*256 + tA] = s1*es*w0;
            cv_b[s*768 + tA*3+0] = s1*evx*w2; cv_b[s*768 + tA*3+1] = s1*evy*w2; cv_b[s*768 + tA*3+2] = s1*evz*w2;
            float p0 = pv_b[s*384 + c*3+0], p1 = pv_b[s*384 + c*3+1], p2 = pv_b[s*384 + c*3+2];
            cs_b[s*256 + tB] = (p0*evx + p1*evy + p2*evz)*w1;
            cv_b[s*768 + tB*3+0] = es*p0*w3; cv_b[s*768 + tB*3+1] = es*p1*w3; cv_b[s*768 + tB*3+2] = es*p2*w3;
        }
        __syncthreads();
        // B4: Wagv (unroll-limited)
        {
            float aatt = bag0, agate = bag1, avals = bag2;
            float v0=0.f, v1=0.f, v2=0.f;
            #pragma unroll 4
            for (int ii = 0; ii < 32; ++ii) {
                int i = (ii + h*8) & 31;
                int cb = h*32 + i;
                float a_s = cs_b[s*256 + cb];
                const float* wrow = &Wagv_s[(h*32+i)*48];
                aatt  += a_s*wrow[o];
                agate += a_s*wrow[16+o];
                avals += a_s*wrow[32+o];
                float wv = Wagv_v[(h*32+i)*16 + o];
                v0 += cv_b[s*768 + cb*3+0]*wv;
                v1 += cv_b[s*768 + cb*3+1]*wv;
                v2 += cv_b[s*768 + cb*3+2]*wv;
            }
            agv_b[s*384 + h*48 + o]      = aatt;
            agv_b[s*384 + h*48 + 16 + o] = agate;
            agv_b[s*384 + h*48 + 32 + o] = avals;
            vv_b[s*384 + c*3+0] = v0; vv_b[s*384 + c*3+1] = v1; vv_b[s*384 + c*3+2] = v2;
        }
        __syncthreads();
        // B5: logit (t<32 -> 4 edges x 8 heads) + gating (all threads)
        if (t < ECON*H_N) {
            int s2 = t >> 3, h2 = t & 7;
            const float* af = &agv_b[s2*384 + h2*48];
            float mu = 0.f;
            #pragma unroll 4
            for (int d2 = 0; d2 < DH_N; ++d2) mu += af[d2];
            mu *= (1.f/DH_N);
            float var = 0.f;
            #pragma unroll 4
            for (int d2 = 0; d2 < DH_N; ++d2) { float dd = af[d2]-mu; var += dd*dd; }
            var *= (1.f/DH_N);
            float rstd = rsqrtf(var + EPS_F);
            float logit = 0.f;
            #pragma unroll 4
            for (int d2 = 0; d2 < DH_N; ++d2) {
                float xn = (af[d2]-mu)*rstd*lna_g[d2] + lna_b[d2];
                logit += xn*Wattn[d2];
            }
            int e2 = e0 + p*ECON + s2;
            if (mask[e2] == 0) logit = NEGMAX;
            attn_raw[h2*(N_Q*K_E) + n*K_E + (k0 + p*ECON + s2)] = logit;
        }
        {
            float vraw = agv_b[s*384 + h*48 + 32 + o];
            float sact = vraw / (1.f + expf(-vraw));
            float g = 1.f / (1.f + expf(-agv_b[s*384 + h*48 + 16 + o]));
            ps_b[s*128 + c] = sact;
            pv_b[s*384 + c*3+0] = vv_b[s*384 + c*3+0]*g;
            pv_b[s*384 + c*3+1] = vv_b[s*384 + c*3+1]*g;
            pv_b[s*384 + c*3+2] = vv_b[s*384 + c*3+2]*g;
        }
        __syncthreads();
        // B6: dtp3
        {
            float es = sh_es[s];
            float evx = sh_ev[s*3+0], evy = sh_ev[s*3+1], evz = sh_ev[s*3+2];
            float s1 = ps_b[s*128 + c];
            cs_b[s*256 + tA] = s1*es;
            cv_b[s*768 + tA*3+0] = s1*evx; cv_b[s*768 + tA*3+1] = s1*evy; cv_b[s*768 + tA*3+2] = s1*evz;
            float p0 = pv_b[s*384 + c*3+0], p1 = pv_b[s*384 + c*3+1], p2 = pv_b[s*384 + c*3+2];
            cs_b[s*256 + tB] = p0*evx + p1*evy + p2*evz;
            cv_b[s*768 + tB*3+0] = es*p0; cv_b[s*768 + tB*3+1] = es*p1; cv_b[s*768 + tB*3+2] = es*p2;
        }
        __syncthreads();
        // B7: Wval -> ebuf (unroll-limited)
        {
            float vs = bval_r, v0=0.f, v1=0.f, v2=0.f;
            #pragma unroll 4
            for (int ii = 0; ii < 32; ++ii) {
                int i = (ii + h*8) & 31;
                int cb = h*32 + i;
                float ws = Wval_s[i*16 + o];
                vs += cs_b[s*256 + cb]*ws;
                float wv = Wval_v[i*16 + o];
                v0 += cv_b[s*768 + cb*3+0]*wv;
                v1 += cv_b[s*768 + cb*3+1]*wv;
                v2 += cv_b[s*768 + cb*3+2]*wv;
            }
            float* eb = &ebuf[(size_t)e*512];
            eb[c] = vs;
            eb[128 + c*3+0] = v0; eb[128 + c*3+1] = v1; eb[128 + c*3+2] = v2;
        }
        __syncthreads();
    }
}

// ---------------------------------------------------------------------------
// E2: per-n softmax (raw logits in attn buffer) + attention-weighted sum
// ---------------------------------------------------------------------------
__global__ __launch_bounds__(128) void k_reduce(
    const float* __restrict__ ebuf,
    float* __restrict__ attn_out,     // in: raw logits, out: probabilities
    float* __restrict__ outs_pre, float* __restrict__ outv_pre)
{
    const int n = blockIdx.x, t = threadIdx.x;
    __shared__ float sh_attn[H_N*K_E];
    if (t < H_N) {
        float lg[K_E];
        float mx = NEGMAX;
        #pragma unroll 4
        for (int k = 0; k < K_E; ++k) {
            lg[k] = attn_out[t*(N_Q*K_E) + n*K_E + k];
            mx = fmaxf(mx, lg[k]);
        }
        float sum = 0.f;
        #pragma unroll 4
        for (int k = 0; k < K_E; ++k) { float p = expf(lg[k]-mx); lg[k] = p; sum += p; }
        float rinv = 1.f/sum;
        #pragma unroll 4
        for (int k = 0; k < K_E; ++k) {
            float a = lg[k]*rinv;
            sh_attn[t*K_E + k] = a;
            attn_out[t*(N_Q*K_E) + n*K_E + k] = a;
        }
    }
    __syncthreads();
    const int h = t >> 4;
    float accs = 0.f, a0 = 0.f, a1 = 0.f, a2 = 0.f;
    #pragma unroll 4
    for (int k = 0; k < K_E; ++k) {
        float a = sh_attn[h*K_E + k];
        const float* eb = &ebuf[(size_t)(n*K_E + k)*512];
        accs += a*eb[t];
        a0 += a*eb[128 + t*3+0];
        a1 += a*eb[128 + t*3+1];
        a2 += a*eb[128 + t*3+2];
    }
    outs_pre[n*D_F + t] = accs;
    outv_pre[(n*D_F+t)*3+0] = a0;
    outv_pre[(n*D_F+t)*3+1] = a1;
    outv_pre[(n*D_F+t)*3+2] = a2;
}

// ---------------------------------------------------------------------------
// Fallback (round-7 monolithic, needs only 16*N*D scratch)
// ---------------------------------------------------------------------------
__global__ __launch_bounds__(256) void k_edge(
    const float* __restrict__ qs2, const float* __restrict__ qv2,
    const float* __restrict__ ksc, const float* __restrict__ kvc,
    const float* __restrict__ eis, const float* __restrict__ eiv,
    const float* __restrict__ eemb,
    const int* __restrict__ mask, const int* __restrict__ knn,
    const float* __restrict__ Wqk_s, const float* __restrict__ Wqk_v, const float* __restrict__ bqk,
    const float* __restrict__ Wdtp, const float* __restrict__ bdtp,
    const float* __restrict__ Wagv_s, const float* __restrict__ bagv, const float* __restrict__ Wagv_v,
    const float* __restrict__ Wattn, const float* __restrict__ lna_g, const float* __restrict__ lna_b,
    const float* __restrict__ Wval_s, const float* __restrict__ Wval_v, const float* __restrict__ bval,
    float* __restrict__ outs_pre, float* __restrict__ outv_pre,
    float* __restrict__ attn_out)
{
    const int n = blockIdx.x, t = threadIdx.x;
    __shared__ float sh_qs[D_F], sh_qv[D_F*3];
    __shared__ float sh_ks[D_F], sh_kv[D_F*3], sh_ee[D_F];
    __shared__ float sh_cs[2*D_F], sh_cv[2*D_F*3];
    __shared__ float sh_ps[D_F], sh_pv[D_F*3];
    __shared__ float sh_w[4*D_F];
    __shared__ float sh_agv[H_N*48], sh_valv[H_N*DH_N*3];
    __shared__ float sh_logit[H_N*K_E], sh_red[H_N*2];
    __shared__ float sh_es, sh_ev[3];
    float m_run = NEGMAX, l_run = 0.f;
    float accs = 0.f, acc0 = 0.f, acc1 = 0.f, acc2 = 0.f;
    if (t < D_F) sh_qs[t] = qs2[n*D_F + t];
    for (int idx = t; idx < D_F*3; idx += 256) sh_qv[idx] = qv2[n*D_F*3 + idx];
    for (int k = 0; k < K_E; ++k) {
        const int e = n*K_E + k;
        const int j = knn[e];
        if (t < D_F) { sh_ks[t] = ksc[j*D_F + t]; sh_ee[t] = eemb[e*D_F + t]; }
        for (int idx = t; idx < D_F*3; idx += 256) sh_kv[idx] = kvc[j*D_F*3 + idx];
        if (t == 0) {
            sh_es = eis[e];
            sh_ev[0] = eiv[e*3+0]; sh_ev[1] = eiv[e*3+1]; sh_ev[2] = eiv[e*3+2];
        }
        __syncthreads();
        {
            const int c = t;
            if (c < D_F) {
                float s1 = sh_qs[c];
                sh_cs[c] = s1 * sh_ks[c];
                #pragma unroll
                for (int x = 0; x < 3; ++x) sh_cv[c*3+x] = s1 * sh_kv[c*3+x];
            } else {
                int d = c - D_F;
                float dot = 0.f;
                #pragma unroll
                for (int x = 0; x < 3; ++x) dot += sh_qv[d*3+x]*sh_kv[d*3+x];
                sh_cs[c] = dot;
                #pragma unroll
                for (int x = 0; x < 3; ++x) sh_cv[c*3+x] = sh_ks[d]*sh_qv[d*3+x];
            }
        }
        __syncthreads();
        #pragma unroll
        for (int r = 0; r < 2; ++r) {
            int oo = t + r*256;
            float acc = bdtp[oo];
            #pragma unroll 2
            for (int i = 0; i < D_F; ++i) acc += sh_ee[i]*Wdtp[i*512 + oo];
            sh_w[oo] = acc;
        }
        if (t < D_F) {
            int h = t >> 4, o = t & 15;
            float as = bqk[o], av0 = 0.f, av1 = 0.f, av2 = 0.f;
            #pragma unroll 4
            for (int i = 0; i < 32; ++i) {
                int cb = h*32 + i;
                float ws = Wqk_s[i*16 + o];
                as += sh_cs[cb]*ws;
                float wv = Wqk_v[i*16 + o];
                av0 += sh_cv[cb*3+0]*wv; av1 += sh_cv[cb*3+1]*wv; av2 += sh_cv[cb*3+2]*wv;
            }
            sh_ps[t] = as;
            sh_pv[t*3+0] = av0; sh_pv[t*3+1] = av1; sh_pv[t*3+2] = av2;
        }
        __syncthreads();
        {
            int h = t >> 5, i = t & 31;
            float es = sh_es;
            if (i < DH_N) {
                int cc = h*DH_N + i;
                float s1 = sh_ps[cc];
                sh_cs[t] = s1*es*sh_w[0*D_F + cc];
                float w2 = sh_w[2*D_F + cc];
                #pragma unroll
                for (int x = 0; x < 3; ++x) sh_cv[t*3+x] = s1*sh_ev[x]*w2;
            } else {
                int cc = h*DH_N + (i - DH_N);
                float dot = 0.f;
                #pragma unroll
                for (int x = 0; x < 3; ++x) dot += sh_pv[cc*3+x]*sh_ev[x];
                sh_cs[t] = dot*sh_w[1*D_F + cc];
                float w3 = sh_w[3*D_F + cc];
                #pragma unroll
                for (int x = 0; x < 3; ++x) sh_cv[t*3+x] = es*sh_pv[cc*3+x]*w3;
            }
        }
        __syncthreads();
        for (int idx = t; idx < H_N*48; idx += 256) {
            int h = idx / 48, oo = idx % 48;
            float acc = bagv[h*48 + oo];
            #pragma unroll 4
            for (int i = 0; i < 32; ++i)
                acc += sh_cs[h*32 + i]*Wagv_s[(h*32 + i)*48 + oo];
            sh_agv[idx] = acc;
        }
        if (t < D_F) {
            int h = t >> 4, o = t & 15;
            float a0 = 0.f, a1 = 0.f, a2 = 0.f;
            #pragma unroll 4
            for (int i = 0; i < 32; ++i) {
                float wv = Wagv_v[(h*32 + i)*16 + o];
                a0 += sh_cv[(h*32+i)*3+0]*wv;
                a1 += sh_cv[(h*32+i)*3+1]*wv;
                a2 += sh_cv[(h*32+i)*3+2]*wv;
            }
            sh_valv[t*3+0] = a0; sh_valv[t*3+1] = a1; sh_valv[t*3+2] = a2;
        }
        __syncthreads();
        if (t < H_N) {
            const float* af = &sh_agv[t*48];
            float mu = 0.f;
            for (int d2 = 0; d2 < DH_N; ++d2) mu += af[d2];
            mu *= (1.f/DH_N);
            float var = 0.f;
            for (int d2 = 0; d2 < DH_N; ++d2) { float dd = af[d2]-mu; var += dd*dd; }
            var *= (1.f/DH_N);
            float rstd = rsqrtf(var + EPS_F);
            float logit = 0.f;
            for (int d2 = 0; d2 < DH_N; ++d2) {
                float xn = (af[d2]-mu)*rstd*lna_g[d2] + lna_b[d2];
                logit += xn*Wattn[d2];
            }
            if (mask[e] == 0) logit = NEGMAX;
            sh_logit[t*K_E + k] = logit;
            float m_new = fmaxf(m_run, logit);
            float alpha = expf(m_run - m_new);
            float p     = expf(logit - m_new);
            l_run = l_run*alpha + p;
            m_run = m_new;
            sh_red[t*2]   = alpha;
            sh_red[t*2+1] = p;
        }
        if (t < D_F) {
            int h = t >> 4, o = t & 15;
            float vraw = sh_agv[h*48 + 32 + o];
            float sact = vraw / (1.f + expf(-vraw));
            float g = 1.f / (1.f + expf(-sh_agv[h*48 + 16 + o]));
            sh_ps[t] = sact;
            #pragma unroll
            for (int x = 0; x < 3; ++x) sh_pv[t*3+x] = sh_valv[t*3+x]*g;
        }
        __syncthreads();
        {
            int h = t >> 5, i = t & 31;
            if (i < DH_N) {
                int cc = h*DH_N + i;
                float s1 = sh_ps[cc];
                sh_cs[t] = s1*sh_es;
                #pragma unroll
                for (int x = 0; x < 3; ++x) sh_cv[t*3+x] = s1*sh_ev[x];
            } else {
                int cc = h*DH_N + (i - DH_N);
                float dot = 0.f;
                #pragma unroll
                for (int x = 0; x < 3; ++x) dot += sh_pv[cc*3+x]*sh_ev[x];
                sh_cs[t] = dot;
                #pragma unroll
                for (int x = 0; x < 3; ++x) sh_cv[t*3+x] = sh_es*sh_pv[cc*3+x];
            }
        }
        __syncthreads();
        if (t < D_F) {
            int h = t >> 4, o = t & 15;
            float vs = bval[o], v0 = 0.f, v1 = 0.f, v2 = 0.f;
            #pragma unroll 4
            for (int i = 0; i < 32; ++i) {
                int cb = h*32 + i;
                float ws = Wval_s[i*16 + o];
                vs += sh_cs[cb]*ws;
                float wv = Wval_v[i*16 + o];
                v0 += sh_cv[cb*3+0]*wv; v1 += sh_cv[cb*3+1]*wv; v2 += sh_cv[cb*3+2]*wv;
            }
            float alpha = sh_red[h*2], p = sh_red[h*2+1];
            accs = accs*alpha + p*vs;
            acc0 = acc0*alpha + p*v0;
            acc1 = acc1*alpha + p*v1;
            acc2 = acc2*alpha + p*v2;
        }
        __syncthreads();
    }
    if (t < H_N) {
        sh_red[t*2]   = m_run;
        sh_red[t*2+1] = 1.f / l_run;
    }
    __syncthreads();
    {
        int h = t >> 5, k = t & 31;
        float a = expf(sh_logit[t] - sh_red[h*2]) * sh_red[h*2+1];
        attn_out[h*(N_Q*K_E) + n*K_E + k] = a;
    }
    if (t < D_F) {
        int h = t >> 4;
        float rinv = sh_red[h*2+1];
        outs_pre[n*D_F + t]     = accs*rinv;
        outv_pre[(n*D_F+t)*3+0] = acc0*rinv;
        outv_pre[(n*D_F+t)*3+1] = acc1*rinv;
        outv_pre[(n*D_F+t)*3+2] = acc2*rinv;
    }
}

// ---------------------------------------------------------------------------
// Kernel D: output eq_linear(Wo) + skip add
// ---------------------------------------------------------------------------
__global__ __launch_bounds__(128) void k_out(
    const float* __restrict__ outs_pre, const float* __restrict__ outv_pre,
    const float* __restrict__ skip_s, const float* __restrict__ skip_v,
    const float* __restrict__ Wo_s, const float* __restrict__ Wo_v, const float* __restrict__ bo,
    float* __restrict__ out0, float* __restrict__ out1)
{
    const int n = blockIdx.x, t = threadIdx.x;
    __shared__ float ps[D_F], pv[D_F*3];
    ps[t] = outs_pre[n*D_F + t];
    #pragma unroll
    for (int x = 0; x < 3; ++x) pv[t*3+x] = outv_pre[(n*D_F + t)*3 + x];
    __syncthreads();
    float acc = bo[t], a0 = 0.f, a1 = 0.f, a2 = 0.f;
    for (int i = 0; i < D_F; ++i) {
        float ws = Wo_s[i*D_F + t]; acc += ps[i]*ws;
        float wv = Wo_v[i*D_F + t];
        a0 += pv[i*3+0]*wv; a1 += pv[i*3+1]*wv; a2 += pv[i*3+2]*wv;
    }
    out0[n*D_F + t] = acc + skip_s[n*D_F + t];
    out1[(n*D_F + t)*3 + 0] = a0 + skip_v[(n*D_F + t)*3 + 0];
    out1[(n*D_F + t)*3 + 1] = a1 + skip_v[(n*D_F + t)*3 + 1];
    out1[(n*D_F + t)*3 + 2] = a2 + skip_v[(n*D_F + t)*3 + 2];
}

// ---------------------------------------------------------------------------
extern "C" void kernel_launch(void* const* d_in, const int* in_sizes, int n_in,
                              void* d_out, int out_size, void* d_ws, size_t ws_size,
                              hipStream_t stream)
{
    (void)in_sizes; (void)n_in; (void)out_size;

    const float* query_s = (const float*)d_in[0];
    const float* query_v = (const float*)d_in[1];
    const float* key_s   = (const float*)d_in[2];
    const float* key_v   = (const float*)d_in[3];
    const float* eis     = (const float*)d_in[4];
    const float* eiv     = (const float*)d_in[5];
    const float* eemb    = (const float*)d_in[6];
    const int*   mask    = (const int*)d_in[7];
    const int*   knn     = (const int*)d_in[8];
    const float* Wq_s    = (const float*)d_in[9];
    const float* Wq_v    = (const float*)d_in[10];
    const float* bq      = (const float*)d_in[11];
    const float* Wk_s    = (const float*)d_in[12];
    const float* Wk_v    = (const float*)d_in[13];
    const float* bk      = (const float*)d_in[14];
    const float* Wqk_s   = (const float*)d_in[15];
    const float* Wqk_v   = (const float*)d_in[16];
    const float* bqk     = (const float*)d_in[17];
    const float* Wdtp    = (const float*)d_in[18];
    const float* bdtp    = (const float*)d_in[19];
    const float* Wagv_s  = (const float*)d_in[20];
    const float* bagv    = (const float*)d_in[21];
    const float* Wagv_v  = (const float*)d_in[22];
    const float* Wattn   = (const float*)d_in[23];
    const float* Wval_s  = (const float*)d_in[24];
    const float* Wval_v  = (const float*)d_in[25];
    const float* bval    = (const float*)d_in[26];
    const float* Wo_s    = (const float*)d_in[27];
    const float* Wo_v    = (const float*)d_in[28];
    const float* bo      = (const float*)d_in[29];
    const float* ln_gs   = (const float*)d_in[30];
    const float* ln_bs   = (const float*)d_in[31];
    const float* ln_gv   = (const float*)d_in[32];
    const float* lna_g   = (const float*)d_in[33];
    const float* lna_b   = (const float*)d_in[34];

    float* out      = (float*)d_out;
    float* out_s    = out;
    float* out_v    = out + N_Q*D_F;
    float* out_attn = out + N_Q*D_F*4;

    float* ws = (float*)d_ws;
    float* qs2      = ws;
    float* qv2      = qs2 + N_Q*D_F;
    float* ksc      = qv2 + N_Q*D_F*3;
    float* kvc      = ksc + N_Q*D_F;
    float* skip_s   = kvc + N_Q*D_F*3;
    float* skip_v   = skip_s + N_Q*D_F;
    float* outs_pre = skip_v + N_Q*D_F*3;
    float* outv_pre = outs_pre + N_Q*D_F;
    float* ebuf     = outv_pre + N_Q*D_F*3;       // N*K*512 floats = 134.2 MB

    const size_t base_floats = (size_t)16*N_Q*D_F;
    const size_t ebuf_floats = (size_t)N_Q*K_E*512;
    const bool   use_bulk = ws_size >= (base_floats + ebuf_floats)*sizeof(float);

    hipLaunchKernelGGL(k_qk, dim3(2*N_Q), dim3(D_F), 0, stream,
                       query_s, query_v, key_s, key_v,
                       Wq_s, Wq_v, bq, Wk_s, Wk_v, bk,
                       ln_gs, ln_bs, ln_gv,
                       qs2, qv2, skip_s, skip_v, ksc, kvc);
    if (use_bulk) {
        hipLaunchKernelGGL(k_edge_bulk, dim3(N_Q*K_E/EPB), dim3(512), 0, stream,
                           qs2, qv2, ksc, kvc, eis, eiv, eemb, mask, knn,
                           Wqk_s, Wqk_v, bqk, Wdtp, bdtp,
                           Wagv_s, bagv, Wagv_v, Wattn, lna_g, lna_b,
                           Wval_s, Wval_v, bval,
                           ebuf, out_attn);
        hipLaunchKernelGGL(k_reduce, dim3(N_Q), dim3(D_F), 0, stream,
                           ebuf, out_attn, outs_pre, outv_pre);
    } else {
        hipLaunchKernelGGL(k_edge, dim3(N_Q), dim3(256), 0, stream,
                           qs2, qv2, ksc, kvc, eis, eiv, eemb, mask, knn,
                           Wqk_s, Wqk_v, bqk, Wdtp, bdtp,
                           Wagv_s, bagv, Wagv_v, Wattn, lna_g, lna_b,
                           Wval_s, Wval_v, bval,
                           outs_pre, outv_pre, out_attn);
    }
    hipLaunchKernelGGL(k_out, dim3(N_Q), dim3(D_F), 0, stream,
                       outs_pre, outv_pre, skip_s, skip_v, Wo_s, Wo_v, bo,
                       out_s, out_v);
}

// Round 12
// 725.184 us; speedup vs baseline: 8.9707x; 1.0402x over previous
//
#include <hip/hip_runtime.h>
#include <hip/hip_bf16.h>
#include <math.h>

#define N_Q 2048
#define K_E 32
#define D_F 128
#define H_N 8
#define DH_N 16
#define EPS_F 1e-5f
#define NEGMAX -3.4028235e38f
#define EPB 8      // edges per E1 block
#define ECON 4     // edges processed concurrently

// Established: fp32 inputs, int32 mask/knn, FP32 output.
// R9/10: forced min-occupancy caps VGPR -> spill. R11: LDS-pipe bound on
// scalar b32 ops -> this round packs all hot LDS traffic into float4 (b128).

// ---------------------------------------------------------------------------
// Kernel A+B: query LN+Wq (blocks [0,N)) / key Wk (blocks [N,2N)).
// Outputs packed float4: .xyz = vector part, .w = scalar part.
// ---------------------------------------------------------------------------
__global__ __launch_bounds__(128) void k_qk(
    const float* __restrict__ qs_in, const float* __restrict__ qv_in,
    const float* __restrict__ ks_in, const float* __restrict__ kv_in,
    const float* __restrict__ Wq_s, const float* __restrict__ Wq_v, const float* __restrict__ bq,
    const float* __restrict__ Wk_s, const float* __restrict__ Wk_v, const float* __restrict__ bk,
    const float* __restrict__ ln_gs, const float* __restrict__ ln_bs, const float* __restrict__ ln_gv,
    float4* __restrict__ q4, float4* __restrict__ k4,
    float* __restrict__ skip_s, float* __restrict__ skip_v)
{
    const int t = threadIdx.x;
    __shared__ float s[D_F], v[D_F*3], sl[D_F], vl[D_F*3];
    if (blockIdx.x < N_Q) {
        const int n = blockIdx.x;
        s[t] = qs_in[n*D_F + t];
        #pragma unroll
        for (int x = 0; x < 3; ++x) v[t*3+x] = qv_in[(n*D_F + t)*3 + x];
        __syncthreads();
        float mu = 0.f;
        for (int i = 0; i < D_F; ++i) mu += s[i];
        mu *= (1.f/D_F);
        float var = 0.f;
        for (int i = 0; i < D_F; ++i) { float d = s[i]-mu; var += d*d; }
        var *= (1.f/D_F);
        float rstd = rsqrtf(var + EPS_F);
        float ssq = 0.f;
        for (int i = 0; i < D_F*3; ++i) ssq += v[i]*v[i];
        float rrms = rsqrtf(ssq*(1.f/D_F) + EPS_F);
        float a = (s[t]-mu)*rstd*ln_gs[t] + ln_bs[t];
        sl[t] = a; skip_s[n*D_F + t] = a;
        float gv = ln_gv[t];
        #pragma unroll
        for (int x = 0; x < 3; ++x) {
            float b = v[t*3+x]*rrms*gv;
            vl[t*3+x] = b; skip_v[(n*D_F + t)*3 + x] = b;
        }
        __syncthreads();
        float acc = bq[t], a0 = 0.f, a1 = 0.f, a2 = 0.f;
        #pragma unroll 4
        for (int i = 0; i < D_F; ++i) {
            float ws = Wq_s[i*D_F + t]; acc += sl[i]*ws;
            float wv = Wq_v[i*D_F + t];
            a0 += vl[i*3+0]*wv; a1 += vl[i*3+1]*wv; a2 += vl[i*3+2]*wv;
        }
        q4[n*D_F + t] = make_float4(a0, a1, a2, acc);
    } else {
        const int n = blockIdx.x - N_Q;
        s[t] = ks_in[n*D_F + t];
        #pragma unroll
        for (int x = 0; x < 3; ++x) v[t*3+x] = kv_in[(n*D_F + t)*3 + x];
        __syncthreads();
        float acc = bk[t], a0 = 0.f, a1 = 0.f, a2 = 0.f;
        #pragma unroll 4
        for (int i = 0; i < D_F; ++i) {
            float ws = Wk_s[i*D_F + t]; acc += s[i]*ws;
            float wv = Wk_v[i*D_F + t];
            a0 += v[i*3+0]*wv; a1 += v[i*3+1]*wv; a2 += v[i*3+2]*wv;
        }
        k4[n*D_F + t] = make_float4(a0, a1, a2, acc);
    }
}

// ---------------------------------------------------------------------------
// E1: bulk edge pipeline, all hot LDS traffic as float4 (b128).
// Block = 8 edges of one n, 512 threads, 4 edges concurrent.
// ---------------------------------------------------------------------------
__global__ __launch_bounds__(512) void k_edge_bulk(
    const float4* __restrict__ q4, const float4* __restrict__ k4,
    const float* __restrict__ eis, const float* __restrict__ eiv,
    const float* __restrict__ eemb,
    const int* __restrict__ mask, const int* __restrict__ knn,
    const float* __restrict__ Wqk_s, const float* __restrict__ Wqk_v, const float* __restrict__ bqk,
    const float* __restrict__ Wdtp, const float* __restrict__ bdtp,
    const float* __restrict__ Wagv_s, const float* __restrict__ bagv, const float* __restrict__ Wagv_v,
    const float* __restrict__ Wattn, const float* __restrict__ lna_g, const float* __restrict__ lna_b,
    const float* __restrict__ Wval_s, const float* __restrict__ Wval_v, const float* __restrict__ bval,
    float4* __restrict__ ebuf4, float* __restrict__ attn_raw)
{
    const int t = threadIdx.x;
    const int e0 = blockIdx.x * EPB;
    const int n  = e0 >> 5;
    const int k0 = e0 & 31;
    const int s = t >> 7, c = t & 127, h = (t >> 4) & 7, o = t & 15;
    const int rot = h * 2;                // 4 heads/wave -> 4 disjoint bank groups

    __shared__ float4 w4[EPB*128];        // 16 KB: (w0,w1,w2,w3) per channel per edge
    __shared__ float4 ch[ECON*256];       // 16 KB: .xyz=cv, .w=cs   (stage-A ee aliased here)
    __shared__ float4 pp[ECON*128];       // 8 KB:  .xyz=pv, .w=ps
    __shared__ float4 kv4[ECON*128];      // 8 KB:  B0 key stage; reused as vv (B4->B5)
    __shared__ float  agv[ECON*384];      // 6 KB
    __shared__ float4 qq[128];            // 2 KB:  .xyz=qv, .w=qs
    __shared__ float  sh_es[ECON], sh_ev[ECON*3];

    if (t < D_F) qq[t] = q4[n*D_F + t];

    // stage A: ee load (transposed, aliased into ch) + w GEMM into w4
    {
        float* ee = (float*)ch;           // [128][8] floats = 4 KB
        { int idx = t;       int m = idx & 7, i = idx >> 3; ee[i*EPB+m] = eemb[(size_t)(e0+m)*D_F + i]; }
        { int idx = t + 512; int m = idx & 7, i = idx >> 3; ee[i*EPB+m] = eemb[(size_t)(e0+m)*D_F + i]; }
        __syncthreads();
        float acc[EPB];
        float b = bdtp[t];
        #pragma unroll
        for (int m = 0; m < EPB; ++m) acc[m] = b;
        #pragma unroll 2
        for (int i = 0; i < D_F; ++i) {
            float wv = Wdtp[i*512 + t];
            #pragma unroll
            for (int m = 0; m < EPB; ++m) acc[m] += ee[i*EPB+m]*wv;
        }
        __syncthreads();                  // all ee reads done -> ch reusable
        float* w4f = (float*)w4;
        const int chn = t & 127, sel = t >> 7;
        #pragma unroll
        for (int m = 0; m < EPB; ++m)
            w4f[(m*128 + chn)*4 + sel] = acc[m];
    }

    const float bqk_r  = bqk[o];
    const float bval_r = bval[o];
    const float bag0 = bagv[h*48 + o];
    const float bag1 = bagv[h*48 + 16 + o];
    const float bag2 = bagv[h*48 + 32 + o];
    const int tA = h*32 + o, tB = h*32 + 16 + o;

    for (int p = 0; p < EPB/ECON; ++p) {
        const int m = p*ECON + s;
        const int e = e0 + m;
        // B0: stage gathered key row (packed) + edge irreps
        {
            const int j = knn[e];
            kv4[s*128 + c] = k4[(size_t)j*D_F + c];
            if (c == 0) {
                sh_es[s] = eis[e];
                sh_ev[s*3+0] = eiv[e*3+0]; sh_ev[s*3+1] = eiv[e*3+1]; sh_ev[s*3+2] = eiv[e*3+2];
            }
        }
        __syncthreads();
        // B1: dtp1
        {
            float4 q = qq[c];
            float4 kk = kv4[s*128 + c];
            float s1 = q.w, kd = kk.w;
            ch[s*256 + c] = make_float4(s1*kk.x, s1*kk.y, s1*kk.z, s1*kd);
            ch[s*256 + 128 + c] = make_float4(kd*q.x, kd*q.y, kd*q.z,
                                              q.x*kk.x + q.y*kk.y + q.z*kk.z);
        }
        __syncthreads();
        // B2: Wqk — one b128 read per iteration
        {
            float as = bqk_r, av0=0.f, av1=0.f, av2=0.f;
            #pragma unroll 4
            for (int ii = 0; ii < 32; ++ii) {
                int i = (ii + rot) & 31;
                float4 cc = ch[s*256 + h*32 + i];
                float ws = Wqk_s[i*16 + o];
                float wv = Wqk_v[i*16 + o];
                as  += cc.w*ws;
                av0 += cc.x*wv; av1 += cc.y*wv; av2 += cc.z*wv;
            }
            pp[s*128 + c] = make_float4(av0, av1, av2, as);
        }
        __syncthreads();
        // B3: dtp2 (weighted); w4[m*128+c] = (w0,w1,w2,w3), c == h*16+o
        {
            float4 w = w4[m*128 + c];
            float4 pv = pp[s*128 + c];
            float es = sh_es[s];
            float evx = sh_ev[s*3+0], evy = sh_ev[s*3+1], evz = sh_ev[s*3+2];
            float s1 = pv.w;
            ch[s*256 + tA] = make_float4(s1*evx*w.z, s1*evy*w.z, s1*evz*w.z, s1*es*w.x);
            float dot = pv.x*evx + pv.y*evy + pv.z*evz;
            ch[s*256 + tB] = make_float4(es*pv.x*w.w, es*pv.y*w.w, es*pv.z*w.w, dot*w.y);
        }
        __syncthreads();
        // B4: Wagv — one b128 read + 4 global weight reads per iteration
        {
            float aatt = bag0, agate = bag1, avals = bag2;
            float v0=0.f, v1=0.f, v2=0.f;
            #pragma unroll 4
            for (int ii = 0; ii < 32; ++ii) {
                int i = (ii + rot) & 31;
                float4 cc = ch[s*256 + h*32 + i];
                const float* wrow = &Wagv_s[(h*32+i)*48];
                aatt  += cc.w*wrow[o];
                agate += cc.w*wrow[16+o];
                avals += cc.w*wrow[32+o];
                float wv = Wagv_v[(h*32+i)*16 + o];
                v0 += cc.x*wv; v1 += cc.y*wv; v2 += cc.z*wv;
            }
            agv[s*384 + h*48 + o]      = aatt;
            agv[s*384 + h*48 + 16 + o] = agate;
            agv[s*384 + h*48 + 32 + o] = avals;
            kv4[s*128 + c] = make_float4(v0, v1, v2, 0.f);   // vv aliased onto kv4
        }
        __syncthreads();
        // B5: logits (t<32: 4 edges x 8 heads) + gating (all threads)
        if (t < ECON*H_N) {
            int s2 = t >> 3, h2 = t & 7;
            const float* af = &agv[s2*384 + h2*48];
            float mu = 0.f;
            #pragma unroll 4
            for (int d2 = 0; d2 < DH_N; ++d2) mu += af[d2];
            mu *= (1.f/DH_N);
            float var = 0.f;
            #pragma unroll 4
            for (int d2 = 0; d2 < DH_N; ++d2) { float dd = af[d2]-mu; var += dd*dd; }
            var *= (1.f/DH_N);
            float rstd = rsqrtf(var + EPS_F);
            float logit = 0.f;
            #pragma unroll 4
            for (int d2 = 0; d2 < DH_N; ++d2) {
                float xn = (af[d2]-mu)*rstd*lna_g[d2] + lna_b[d2];
                logit += xn*Wattn[d2];
            }
            int e2 = e0 + p*ECON + s2;
            if (mask[e2] == 0) logit = NEGMAX;
            attn_raw[h2*(N_Q*K_E) + n*K_E + (k0 + p*ECON + s2)] = logit;
        }
        {
            float vraw = agv[s*384 + h*48 + 32 + o];
            float sact = vraw / (1.f + expf(-vraw));
            float g = 1.f / (1.f + expf(-agv[s*384 + h*48 + 16 + o]));
            float4 vv = kv4[s*128 + c];
            pp[s*128 + c] = make_float4(vv.x*g, vv.y*g, vv.z*g, sact);
        }
        __syncthreads();
        // B6: dtp3
        {
            float4 pv = pp[s*128 + c];
            float es = sh_es[s];
            float evx = sh_ev[s*3+0], evy = sh_ev[s*3+1], evz = sh_ev[s*3+2];
            float s1 = pv.w;
            ch[s*256 + tA] = make_float4(s1*evx, s1*evy, s1*evz, s1*es);
            float dot = pv.x*evx + pv.y*evy + pv.z*evz;
            ch[s*256 + tB] = make_float4(es*pv.x, es*pv.y, es*pv.z, dot);
        }
        __syncthreads();
        // B7: Wval -> packed coalesced ebuf
        {
            float vs = bval_r, v0=0.f, v1=0.f, v2=0.f;
            #pragma unroll 4
            for (int ii = 0; ii < 32; ++ii) {
                int i = (ii + rot) & 31;
                float4 cc = ch[s*256 + h*32 + i];
                float ws = Wval_s[i*16 + o];
                float wv = Wval_v[i*16 + o];
                vs += cc.w*ws;
                v0 += cc.x*wv; v1 += cc.y*wv; v2 += cc.z*wv;
            }
            ebuf4[(size_t)e*D_F + c] = make_float4(v0, v1, v2, vs);
        }
        __syncthreads();
    }
}

// ---------------------------------------------------------------------------
// k_finish: per-n softmax + attention-weighted sum + Wo linear + skip add
// ---------------------------------------------------------------------------
__global__ __launch_bounds__(128) void k_finish(
    const float4* __restrict__ ebuf4,
    float* __restrict__ attn_out,     // in: raw logits, out: probabilities
    const float* __restrict__ skip_s, const float* __restrict__ skip_v,
    const float* __restrict__ Wo_s, const float* __restrict__ Wo_v, const float* __restrict__ bo,
    float* __restrict__ out0, float* __restrict__ out1)
{
    const int n = blockIdx.x, t = threadIdx.x;
    __shared__ float sh_attn[H_N*K_E];
    __shared__ float4 sh_o[D_F];          // .xyz = outv_pre, .w = outs_pre
    if (t < H_N) {
        float lg[K_E];
        float mx = NEGMAX;
        #pragma unroll 4
        for (int k = 0; k < K_E; ++k) {
            lg[k] = attn_out[t*(N_Q*K_E) + n*K_E + k];
            mx = fmaxf(mx, lg[k]);
        }
        float sum = 0.f;
        #pragma unroll 4
        for (int k = 0; k < K_E; ++k) { float p = expf(lg[k]-mx); lg[k] = p; sum += p; }
        float rinv = 1.f/sum;
        #pragma unroll 4
        for (int k = 0; k < K_E; ++k) {
            float a = lg[k]*rinv;
            sh_attn[t*K_E + k] = a;
            attn_out[t*(N_Q*K_E) + n*K_E + k] = a;
        }
    }
    __syncthreads();
    const int h = t >> 4;
    float accs = 0.f, a0 = 0.f, a1 = 0.f, a2 = 0.f;
    #pragma unroll 4
    for (int k = 0; k < K_E; ++k) {
        float a = sh_attn[h*K_E + k];
        float4 eb = ebuf4[(size_t)(n*K_E + k)*D_F + t];
        accs += a*eb.w;
        a0 += a*eb.x; a1 += a*eb.y; a2 += a*eb.z;
    }
    sh_o[t] = make_float4(a0, a1, a2, accs);
    __syncthreads();
    float acc = bo[t], o0 = 0.f, o1 = 0.f, o2 = 0.f;
    #pragma unroll 4
    for (int i = 0; i < D_F; ++i) {
        float4 pv = sh_o[i];
        float ws = Wo_s[i*D_F + t]; acc += pv.w*ws;
        float wv = Wo_v[i*D_F + t];
        o0 += pv.x*wv; o1 += pv.y*wv; o2 += pv.z*wv;
    }
    out0[n*D_F + t] = acc + skip_s[n*D_F + t];
    out1[(n*D_F + t)*3 + 0] = o0 + skip_v[(n*D_F + t)*3 + 0];
    out1[(n*D_F + t)*3 + 1] = o1 + skip_v[(n*D_F + t)*3 + 1];
    out1[(n*D_F + t)*3 + 2] = o2 + skip_v[(n*D_F + t)*3 + 2];
}

// ---------------------------------------------------------------------------
extern "C" void kernel_launch(void* const* d_in, const int* in_sizes, int n_in,
                              void* d_out, int out_size, void* d_ws, size_t ws_size,
                              hipStream_t stream)
{
    (void)in_sizes; (void)n_in; (void)out_size; (void)ws_size;

    const float* query_s = (const float*)d_in[0];
    const float* query_v = (const float*)d_in[1];
    const float* key_s   = (const float*)d_in[2];
    const float* key_v   = (const float*)d_in[3];
    const float* eis     = (const float*)d_in[4];
    const float* eiv     = (const float*)d_in[5];
    const float* eemb    = (const float*)d_in[6];
    const int*   mask    = (const int*)d_in[7];
    const int*   knn     = (const int*)d_in[8];
    const float* Wq_s    = (const float*)d_in[9];
    const float* Wq_v    = (const float*)d_in[10];
    const float* bq      = (const float*)d_in[11];
    const float* Wk_s    = (const float*)d_in[12];
    const float* Wk_v    = (const float*)d_in[13];
    const float* bk      = (const float*)d_in[14];
    const float* Wqk_s   = (const float*)d_in[15];
    const float* Wqk_v   = (const float*)d_in[16];
    const float* bqk     = (const float*)d_in[17];
    const float* Wdtp    = (const float*)d_in[18];
    const float* bdtp    = (const float*)d_in[19];
    const float* Wagv_s  = (const float*)d_in[20];
    const float* bagv    = (const float*)d_in[21];
    const float* Wagv_v  = (const float*)d_in[22];
    const float* Wattn   = (const float*)d_in[23];
    const float* Wval_s  = (const float*)d_in[24];
    const float* Wval_v  = (const float*)d_in[25];
    const float* bval    = (const float*)d_in[26];
    const float* Wo_s    = (const float*)d_in[27];
    const float* Wo_v    = (const float*)d_in[28];
    const float* bo      = (const float*)d_in[29];
    const float* ln_gs   = (const float*)d_in[30];
    const float* ln_bs   = (const float*)d_in[31];
    const float* ln_gv   = (const float*)d_in[32];
    const float* lna_g   = (const float*)d_in[33];
    const float* lna_b   = (const float*)d_in[34];

    float* out      = (float*)d_out;
    float* out_s    = out;
    float* out_v    = out + N_Q*D_F;
    float* out_attn = out + N_Q*D_F*4;

    float* ws = (float*)d_ws;
    float4* q4     = (float4*)ws;                      // N*128 f4 = 4 MB
    float4* k4     = q4 + N_Q*D_F;                     // 4 MB
    float*  skip_s = (float*)(k4 + N_Q*D_F);           // 1 MB
    float*  skip_v = skip_s + N_Q*D_F;                 // 3 MB
    float4* ebuf4  = (float4*)(skip_v + N_Q*D_F*3);    // N*K*128 f4 = 134 MB

    hipLaunchKernelGGL(k_qk, dim3(2*N_Q), dim3(D_F), 0, stream,
                       query_s, query_v, key_s, key_v,
                       Wq_s, Wq_v, bq, Wk_s, Wk_v, bk,
                       ln_gs, ln_bs, ln_gv,
                       q4, k4, skip_s, skip_v);
    hipLaunchKernelGGL(k_edge_bulk, dim3(N_Q*K_E/EPB), dim3(512), 0, stream,
                       q4, k4, eis, eiv, eemb, mask, knn,
                       Wqk_s, Wqk_v, bqk, Wdtp, bdtp,
                       Wagv_s, bagv, Wagv_v, Wattn, lna_g, lna_b,
                       Wval_s, Wval_v, bval,
                       ebuf4, out_attn);
    hipLaunchKernelGGL(k_finish, dim3(N_Q), dim3(D_F), 0, stream,
                       ebuf4, out_attn, skip_s, skip_v, Wo_s, Wo_v, bo,
                       out_s, out_v);
}